// Round 15
// baseline (334.032 us; speedup 1.0000x reference)
//
#include <hip/hip_runtime.h>
#include <float.h>
#include <stdint.h>

#define DIM 512
#define BM 256
#define BN 256
#define NSPLIT 64
#define NUM_CLASSES 1000
#define MARGIN 0.04f

typedef unsigned short ushort_t;
typedef __attribute__((ext_vector_type(4))) float fvec4;
typedef __attribute__((ext_vector_type(8))) __bf16 bvec8;
typedef __attribute__((ext_vector_type(4))) int ivec4;

#define AS1 __attribute__((address_space(1)))
#define AS3 __attribute__((address_space(3)))

__device__ inline ushort_t bf16_rne(float f) {
  uint32_t u = __builtin_bit_cast(uint32_t, f);
  uint32_t r = u + 0x7fffu + ((u >> 16) & 1u);
  return (ushort_t)(r >> 16);
}

// ---------- prep: rnorm + f32 -> bf16 (RNE) plane ----------
__global__ __launch_bounds__(256) void prep_bf16(
    const float* __restrict__ src, float* __restrict__ rnorm_out,
    ushort_t* __restrict__ hi, int rows, int scale) {
  int row = blockIdx.x * 4 + (threadIdx.x >> 6);
  int l = threadIdx.x & 63;
  if (row >= rows) return;
  const float4* p = (const float4*)(src + (size_t)row * DIM);
  float4 a = p[l * 2], b = p[l * 2 + 1];
  float rn = 1.0f;
  if (scale) {
    float s = a.x*a.x + a.y*a.y + a.z*a.z + a.w*a.w
            + b.x*b.x + b.y*b.y + b.z*b.z + b.w*b.w;
    #pragma unroll
    for (int off = 1; off < 64; off <<= 1) s += __shfl_xor(s, off, 64);
    rn = 1.0f / fmaxf(sqrtf(s), 1e-12f);
    if (rnorm_out && l == 0) rnorm_out[row] = rn;
  }
  if (!hi) return;
  float v[8] = {a.x*rn, a.y*rn, a.z*rn, a.w*rn, b.x*rn, b.y*rn, b.z*rn, b.w*rn};
  ivec4 hw;
  #pragma unroll
  for (int t = 0; t < 4; ++t) {
    ushort_t h0 = bf16_rne(v[2*t]), h1 = bf16_rne(v[2*t+1]);
    hw[t] = (int)((uint32_t)h0 | ((uint32_t)h1 << 16));
  }
  *(ivec4*)(hi + (size_t)row * DIM + l * 8) = hw;
}

// ---------- screen (main): 8-wave 256x256 tile, full 2-phase-per-half schedule ----------
// R14 (297us, MfmaUtil 35.7): one barrier per half -> waves drift and re-bunch at the
// 10-read LDS burst. R15 completes the m201-style phase split: per half,
//   ph0: {vmcnt(8)+s_barrier, read A0-3+B0-3 (8), stage q0, setprio, 16 MFMA}
//   ph1: {s_barrier,           read B4-7   (4), stage q1, setprio, 16 MFMA}
// Counted vmcnt never drains in-loop (T4); stages run 3 halves ahead; tail stages
// clamp to last half (idempotent rewrites). Hazard proof: ph1 reads are lgkm-consumed
// before its MFMA cluster, which precedes the next half's barrier; stage for buffer
// (H-1)&3 issues only after that barrier retires its readers.
__global__ __launch_bounds__(512)
__attribute__((amdgpu_waves_per_eu(2, 2)))
void nn_mfma8(
    const ushort_t* __restrict__ qh, const ushort_t* __restrict__ xh,
    int2* __restrict__ keys, int N, int nPerSplit) {
  __shared__ __align__(1024) char smem[131072];   // 4 half-buffers x 32KB
  const int tid = threadIdx.x;
  const int l = tid & 63, w = tid >> 6;           // 8 waves
  const int wm = w >> 1, wn = w & 1;              // 4M x 2N; wave tile 64 x 128
  const int lrow = l & 15, lk8 = (l >> 4) * 8;
  const int split = blockIdx.x;
  const int m0 = blockIdx.y * BM;
  const int nStart = split * nPerSplit;
  const int nEnd = min(nStart + nPerSplit, N);
  const int nTiles = (nEnd - nStart + 255) >> 8;
  const int nH = nTiles * 16;                     // 16 K-halves per 256-wide n-tile

  uint32_t K1[16], K2[16];
  #pragma unroll
  for (int s = 0; s < 16; ++s) { K1[s] = 0u; K2[s] = 0u; }

  // stage 2 blobs (part q) of half Hs; blob b: 0..15 = A, 16..31 = B; dest = base + b*1KB
  auto STAGE2 = [&](int Hs, int q) {
    Hs = min(Hs, nH - 1);
    char* base = smem + (Hs & 3) * 32768;
    int k0 = (Hs & 15) * 32;
    int sn0 = nStart + ((Hs >> 4) << 8);
    #pragma unroll
    for (int t = 0; t < 2; ++t) {
      int b = 4 * w + 2 * q + t;
      size_t off;
      const ushort_t* src;
      if (b < 16) { src = qh; off = (size_t)(m0 + 16 * b + lrow) * DIM + k0 + lk8; }
      else        { src = xh; off = (size_t)min(sn0 + 16 * (b - 16) + lrow, N - 1) * DIM + k0 + lk8; }
      __builtin_amdgcn_global_load_lds((const AS1 int*)(src + off), (AS3 int*)(base + b * 1024), 16, 0, 0);
    }
  };

  // prologue: 3 halves in flight (12 loads/wave)
  STAGE2(0, 0); STAGE2(0, 1);
  STAGE2(1, 0); STAGE2(1, 1);
  STAGE2(2, 0); STAGE2(2, 1);

  fvec4 acc[4][8];
  const fvec4 zero4 = {0.f, 0.f, 0.f, 0.f};

  #pragma unroll 1
  for (int H = 0; H < nH; ++H) {
    if ((H & 15) == 0) {
      #pragma unroll
      for (int i = 0; i < 4; ++i)
        #pragma unroll
        for (int j = 0; j < 8; ++j) acc[i][j] = zero4;
    }
    const char* rb = smem + (H & 3) * 32768;

    // ---- phase 0: counted-vmcnt barrier, A(4)+B(4) reads, stage q0, 16 MFMA ----
    asm volatile("s_waitcnt vmcnt(8)\n\ts_barrier" ::: "memory");
    __builtin_amdgcn_sched_barrier(0);
    bvec8 Af[4], Bf[4];
    #pragma unroll
    for (int i = 0; i < 4; ++i)
      Af[i] = __builtin_bit_cast(bvec8, *(const ivec4*)(rb + (wm * 4 + i) * 1024 + l * 16));
    #pragma unroll
    for (int j = 0; j < 4; ++j)
      Bf[j] = __builtin_bit_cast(bvec8, *(const ivec4*)(rb + 16384 + (wn * 8 + j) * 1024 + l * 16));
    STAGE2(H + 3, 0);
    __builtin_amdgcn_s_setprio(1);
    #pragma unroll
    for (int i = 0; i < 4; ++i)
      #pragma unroll
      for (int j = 0; j < 4; ++j)
        acc[i][j] = __builtin_amdgcn_mfma_f32_16x16x32_bf16(Af[i], Bf[j], acc[i][j], 0, 0, 0);
    __builtin_amdgcn_s_setprio(0);

    // ---- phase 1: barrier, B(4) reads (A reused), stage q1, 16 MFMA ----
    __builtin_amdgcn_s_barrier();
    bvec8 Bg[4];
    #pragma unroll
    for (int j = 0; j < 4; ++j)
      Bg[j] = __builtin_bit_cast(bvec8, *(const ivec4*)(rb + 16384 + (wn * 8 + 4 + j) * 1024 + l * 16));
    STAGE2(H + 3, 1);
    __builtin_amdgcn_s_setprio(1);
    #pragma unroll
    for (int i = 0; i < 4; ++i)
      #pragma unroll
      for (int j = 0; j < 4; ++j)
        acc[i][4 + j] = __builtin_amdgcn_mfma_f32_16x16x32_bf16(Af[i], Bg[j], acc[i][4 + j], 0, 0, 0);
    __builtin_amdgcn_s_setprio(0);

    // ---- end of n-tile: branchless top-2 fold ----
    if ((H & 15) == 15) {
      int n0 = nStart + ((H >> 4) << 8);
      uint32_t msk[8], nb[8];
      #pragma unroll
      for (int j = 0; j < 8; ++j) {
        int n = n0 + wn * 128 + j * 16 + lrow;
        bool valid = n < nEnd;
        msk[j] = valid ? 0xFFFFF800u : 0u;
        nb[j]  = valid ? (uint32_t)(2047 - (n - nStart)) : 0u;
      }
      #pragma unroll
      for (int i = 0; i < 4; ++i)
        #pragma unroll
        for (int j = 0; j < 8; ++j)
          #pragma unroll
          for (int r = 0; r < 4; ++r) {
            int ss = i * 4 + r;
            uint32_t key = (__builtin_bit_cast(uint32_t, acc[i][j][r] + 8.0f) & msk[j]) | nb[j];
            uint32_t lo = min(K1[ss], key);
            K1[ss] = max(K1[ss], key);
            K2[ss] = max(K2[ss], lo);
          }
    }
  }

  // cross-lane top-2 merge over the 16 lanes sharing each query row
  #pragma unroll
  for (int s = 0; s < 16; ++s) {
    uint32_t k1 = K1[s], k2 = K2[s];
    #pragma unroll
    for (int off = 1; off < 16; off <<= 1) {
      uint32_t o1 = (uint32_t)__shfl_xor((int)k1, off, 64);
      uint32_t o2 = (uint32_t)__shfl_xor((int)k2, off, 64);
      uint32_t nk2 = max(min(k1, o1), max(k2, o2));
      k1 = max(k1, o1);
      k2 = nk2;
    }
    if (lrow == 0) {
      int m = m0 + wm * 64 + (s >> 2) * 16 + (l >> 4) * 4 + (s & 3);
      keys[((size_t)m * NSPLIT + split) * 2 + wn] = make_int2((int)k1, (int)k2);
    }
  }
}

// ---------- fallback (no-ws path): R13 structure, f32 on-the-fly ----------
__global__ __launch_bounds__(256)
__attribute__((amdgpu_waves_per_eu(2, 2)))
void nn_mfma_fb(
    const float* __restrict__ qf, const float* __restrict__ xf,
    const float* __restrict__ rnorm,
    int2* __restrict__ keys, int N, int nPerSplit) {
  __shared__ __align__(1024) char smem[49152];
  const int tid = threadIdx.x;
  const int l = tid & 63, wv = tid >> 6;
  const int lrow = l & 15;
  const int split = blockIdx.x;
  const int m0 = blockIdx.y * BM;
  const int nStart = split * nPerSplit;
  const int nEnd = min(nStart + nPerSplit, N);

  uint32_t K1[16], K2[16];
  #pragma unroll
  for (int s = 0; s < 16; ++s) { K1[s] = 0u; K2[s] = 0u; }
  const fvec4 zero4 = {0.f, 0.f, 0.f, 0.f};

  auto STAGE = [&](int c, int sn0, int sk0) {
    char* base = smem + c * 24576;
    #pragma unroll
    for (int u = 0; u < 6; ++u) {
      int unit = tid + 256 * u;
      if (unit < 1024) {
        int row = unit >> 2, kg = unit & 3;
        int boff_l = (row >> 4) * 1024 + kg * 256 + (row & 15) * 16;
        const float* s0 = qf + (size_t)(m0 + row) * DIM + sk0 + kg * 8;
        float4 a0 = *(const float4*)s0, a1 = *(const float4*)(s0 + 4);
        float vv[8] = {a0.x,a0.y,a0.z,a0.w,a1.x,a1.y,a1.z,a1.w};
        ivec4 hw;
        #pragma unroll
        for (int t = 0; t < 4; ++t) {
          ushort_t h0 = bf16_rne(vv[2*t]), h1 = bf16_rne(vv[2*t+1]);
          hw[t] = (int)((uint32_t)h0 | ((uint32_t)h1 << 16));
        }
        *(ivec4*)(base + boff_l) = hw;
      } else {
        int u2 = unit - 1024;
        int row = u2 >> 2, kg = u2 & 3;
        int boff_l = 16384 + (row >> 4) * 1024 + kg * 256 + (row & 15) * 16;
        int gr = min(sn0 + row, N - 1);
        float rn = rnorm[gr];
        const float* s0 = xf + (size_t)gr * DIM + sk0 + kg * 8;
        float4 a0 = *(const float4*)s0, a1 = *(const float4*)(s0 + 4);
        float vv[8] = {a0.x*rn,a0.y*rn,a0.z*rn,a0.w*rn,a1.x*rn,a1.y*rn,a1.z*rn,a1.w*rn};
        ivec4 hw;
        #pragma unroll
        for (int t = 0; t < 4; ++t) {
          ushort_t h0 = bf16_rne(vv[2*t]), h1 = bf16_rne(vv[2*t+1]);
          hw[t] = (int)((uint32_t)h0 | ((uint32_t)h1 << 16));
        }
        *(ivec4*)(base + boff_l) = hw;
      }
    }
  };

  const int nTiles = (nEnd - nStart + 127) >> 7;
  const int S = nTiles * 16;
  STAGE(0, nStart, 0);
  if (S > 1) STAGE(1 % 3, nStart, 32);
  __syncthreads();

  fvec4 acc[4][8];
  #pragma unroll 1
  for (int s = 0; s < S; ++s) {
    if ((s & 15) == 0) {
      #pragma unroll
      for (int i = 0; i < 4; ++i)
        #pragma unroll
        for (int j = 0; j < 8; ++j) acc[i][j] = zero4;
    }
    if (s + 2 < S) STAGE((s + 2) % 3, nStart + (((s + 2) >> 4) * 128), ((s + 2) & 15) * 32);
    const char* rb = smem + (s % 3) * 24576;
    bvec8 Ah[4], Bh[8];
    #pragma unroll
    for (int i = 0; i < 4; ++i)
      Ah[i] = __builtin_bit_cast(bvec8, *(const ivec4*)(rb + (wv*4 + i) * 1024 + l * 16));
    #pragma unroll
    for (int j = 0; j < 8; ++j)
      Bh[j] = __builtin_bit_cast(bvec8, *(const ivec4*)(rb + 16384 + j * 1024 + l * 16));
    #pragma unroll
    for (int i = 0; i < 4; ++i)
      #pragma unroll
      for (int j = 0; j < 8; ++j)
        acc[i][j] = __builtin_amdgcn_mfma_f32_16x16x32_bf16(Ah[i], Bh[j], acc[i][j], 0, 0, 0);
    if ((s & 15) == 15) {
      int n0 = nStart + ((s >> 4) * 128);
      uint32_t msk[8], nb[8];
      #pragma unroll
      for (int j = 0; j < 8; ++j) {
        int n = n0 + j * 16 + lrow;
        bool valid = n < nEnd;
        msk[j] = valid ? 0xFFFFF800u : 0u;
        nb[j]  = valid ? (uint32_t)(2047 - (n - nStart)) : 0u;
      }
      #pragma unroll
      for (int i = 0; i < 4; ++i)
        #pragma unroll
        for (int j = 0; j < 8; ++j)
          #pragma unroll
          for (int r = 0; r < 4; ++r) {
            int ss = i * 4 + r;
            uint32_t key = (__builtin_bit_cast(uint32_t, acc[i][j][r] + 8.0f) & msk[j]) | nb[j];
            uint32_t lo = min(K1[ss], key);
            K1[ss] = max(K1[ss], key);
            K2[ss] = max(K2[ss], lo);
          }
    }
    __syncthreads();
  }

  #pragma unroll
  for (int s = 0; s < 16; ++s) {
    uint32_t k1 = K1[s], k2 = K2[s];
    #pragma unroll
    for (int off = 1; off < 16; off <<= 1) {
      uint32_t o1 = (uint32_t)__shfl_xor((int)k1, off, 64);
      uint32_t o2 = (uint32_t)__shfl_xor((int)k2, off, 64);
      uint32_t nk2 = max(min(k1, o1), max(k2, o2));
      k1 = max(k1, o1);
      k2 = nk2;
    }
    if (lrow == 0) {
      int m = m0 + wv * 64 + (s >> 2) * 16 + (l >> 4) * 4 + (s & 3);
      keys[((size_t)m * NSPLIT + split) * 2 + 0] = make_int2((int)k1, (int)k2);
      keys[((size_t)m * NSPLIT + split) * 2 + 1] = make_int2(0, 0);
    }
  }
}

// ---------- finalize: unpack 256 candidate slots, exact f32 rescore, one-hot ----------
__global__ __launch_bounds__(256) void finalize_kernel(
    const int2* __restrict__ keys,
    const float* __restrict__ qf, const float* __restrict__ xf,
    const float* __restrict__ rnorm, const int* __restrict__ y,
    int* __restrict__ out, int nPerSplit) {
  int m = blockIdx.x;
  int tid = threadIdx.x, l = tid & 63, w = tid >> 6;
  __shared__ float sv[256]; __shared__ int si[256];
  __shared__ float swm[4];
  __shared__ float swv[4]; __shared__ int swi[4];
  __shared__ int s_label;
  {
    int slot = tid >> 1;                       // split*2 + wn
    int2 kk = keys[(size_t)m * 128 + slot];
    uint32_t k = (tid & 1) ? (uint32_t)kk.y : (uint32_t)kk.x;
    float v; int idx;
    if (k == 0) { v = -FLT_MAX; idx = 0x7fffffff; }
    else {
      v = __builtin_bit_cast(float, k & 0xFFFFF800u) - 8.0f;
      idx = (slot >> 1) * nPerSplit + 2047 - (int)(k & 0x7FFu);
    }
    sv[tid] = v; si[tid] = idx;
  }
  __syncthreads();
  float v = sv[tid];
  #pragma unroll
  for (int off = 1; off < 64; off <<= 1) v = fmaxf(v, __shfl_xor(v, off, 64));
  if (l == 0) swm[w] = v;
  __syncthreads();
  float svmax = fmaxf(fmaxf(swm[0], swm[1]), fmaxf(swm[2], swm[3]));
  float thresh = svmax - MARGIN;
  float bestv = -FLT_MAX; int besti = 0x7fffffff;
  for (int cc = 0; cc < 64; ++cc) {
    int c = w * 64 + cc;
    float av = sv[c]; int idx = si[c];
    if (av < thresh) continue;  // wave-uniform branch
    const float4* qp = (const float4*)(qf + (size_t)m * DIM);
    const float4* xp = (const float4*)(xf + (size_t)idx * DIM);
    float s = 0.f;
    #pragma unroll
    for (int t = 0; t < 2; ++t) {
      float4 qa = qp[l * 2 + t], xa = xp[l * 2 + t];
      s += qa.x*xa.x + qa.y*xa.y + qa.z*xa.z + qa.w*xa.w;
    }
    #pragma unroll
    for (int off = 1; off < 64; off <<= 1) s += __shfl_xor(s, off, 64);
    float ev = s * rnorm[idx];
    if (ev > bestv || (ev == bestv && idx < besti)) { bestv = ev; besti = idx; }
  }
  if (l == 0) { swv[w] = bestv; swi[w] = besti; }
  __syncthreads();
  if (tid == 0) {
    float bv = swv[0]; int bi = swi[0];
    #pragma unroll
    for (int k = 1; k < 4; ++k)
      if (swv[k] > bv || (swv[k] == bv && swi[k] < bi)) { bv = swv[k]; bi = swi[k]; }
    s_label = y[bi];
  }
  __syncthreads();
  int label = s_label;
  for (int c = tid; c < NUM_CLASSES; c += 256)
    out[(size_t)m * NUM_CLASSES + c] = (c == label) ? 1 : 0;
}

extern "C" void kernel_launch(void* const* d_in, const int* in_sizes, int n_in,
                              void* d_out, int out_size, void* d_ws, size_t ws_size,
                              hipStream_t stream) {
  const float* x = (const float*)d_in[0];   // [N, 512]
  const int*   y = (const int*)d_in[1];     // [N]
  const float* q = (const float*)d_in[2];   // [M, 512]
  int N = in_sizes[0] / DIM;                // 100000
  int M = in_sizes[2] / DIM;                // 2048
  int* out = (int*)d_out;

  // workspace layout
  size_t off = 0;
  float* rnorm = (float*)((char*)d_ws + off); off += (((size_t)N * 4 + 1023) / 1024) * 1024;
  int2* keys   = (int2*)((char*)d_ws + off);  off += (size_t)M * NSPLIT * 2 * 8;
  ushort_t* qh = (ushort_t*)((char*)d_ws + off); off += (size_t)M * DIM * 2;
  ushort_t* xh = (ushort_t*)((char*)d_ws + off); off += (size_t)N * DIM * 2;
  bool pre = (ws_size >= off);

  int nPerSplit = (N + NSPLIT - 1) / NSPLIT;  // 1563 (< 2048: fits 11-bit key index)

  if (pre) {
    prep_bf16<<<(N + 3) / 4, 256, 0, stream>>>(x, rnorm, xh, N, 1);
    prep_bf16<<<(M + 3) / 4, 256, 0, stream>>>(q, nullptr, qh, M, 0);
    dim3 grid(NSPLIT, M / BM);                // 64 x 8 = 512 blocks, 1/CU, 2 rounds
    nn_mfma8<<<grid, 512, 0, stream>>>(qh, xh, keys, N, nPerSplit);
  } else {
    prep_bf16<<<(N + 3) / 4, 256, 0, stream>>>(x, rnorm, nullptr, N, 1);
    dim3 gridf(NSPLIT, M / BM);               // fallback: 256-thread R13 structure
    nn_mfma_fb<<<gridf, 256, 0, stream>>>(q, x, rnorm, keys, N, nPerSplit);
  }
  finalize_kernel<<<M, 256, 0, stream>>>(keys, q, x, rnorm, y, out, nPerSplit);
}

// Round 17
// 322.799 us; speedup vs baseline: 1.0348x; 1.0348x over previous
//
#include <hip/hip_runtime.h>
#include <float.h>
#include <stdint.h>

#define DIM 512
#define BM 256
#define BN 256
#define NSPLIT 64
#define NUM_CLASSES 1000
#define MARGIN 0.04f

typedef unsigned short ushort_t;
typedef __attribute__((ext_vector_type(4))) float fvec4;
typedef __attribute__((ext_vector_type(8))) __bf16 bvec8;
typedef __attribute__((ext_vector_type(4))) int ivec4;

#define AS1 __attribute__((address_space(1)))
#define AS3 __attribute__((address_space(3)))

__device__ inline ushort_t bf16_rne(float f) {
  uint32_t u = __builtin_bit_cast(uint32_t, f);
  uint32_t r = u + 0x7fffu + ((u >> 16) & 1u);
  return (ushort_t)(r >> 16);
}

// ---------- prep: rnorm + f32 -> bf16 (RNE) plane ----------
__global__ __launch_bounds__(256) void prep_bf16(
    const float* __restrict__ src, float* __restrict__ rnorm_out,
    ushort_t* __restrict__ hi, int rows, int scale) {
  int row = blockIdx.x * 4 + (threadIdx.x >> 6);
  int l = threadIdx.x & 63;
  if (row >= rows) return;
  const float4* p = (const float4*)(src + (size_t)row * DIM);
  float4 a = p[l * 2], b = p[l * 2 + 1];
  float rn = 1.0f;
  if (scale) {
    float s = a.x*a.x + a.y*a.y + a.z*a.z + a.w*a.w
            + b.x*b.x + b.y*b.y + b.z*b.z + b.w*b.w;
    #pragma unroll
    for (int off = 1; off < 64; off <<= 1) s += __shfl_xor(s, off, 64);
    rn = 1.0f / fmaxf(sqrtf(s), 1e-12f);
    if (rnorm_out && l == 0) rnorm_out[row] = rn;
  }
  if (!hi) return;
  float v[8] = {a.x*rn, a.y*rn, a.z*rn, a.w*rn, b.x*rn, b.y*rn, b.z*rn, b.w*rn};
  ivec4 hw;
  #pragma unroll
  for (int t = 0; t < 4; ++t) {
    ushort_t h0 = bf16_rne(v[2*t]), h1 = bf16_rne(v[2*t+1]);
    hw[t] = (int)((uint32_t)h0 | ((uint32_t)h1 << 16));
  }
  *(ivec4*)(hi + (size_t)row * DIM + l * 8) = hw;
}

// ---------- screen (main): 8-wave 256x256, phase schedule + tile-exact splits ----------
// R16 failed; audit cleared splits/role-split. The ONLY factor correlated with both
// unexplained failures (R6, R16) vs all ten passes is the +8 bias folded into the
// MFMA accumulator INIT. R17 bisect: keep R16's splits + swizzle + role-split
// verbatim, revert ONLY the numeric path to the proven one (acc init = 0, fold
// computes bits(acc + 8.0f)). If this passes, bias-init is confirmed culprit.
__global__ __launch_bounds__(512)
__attribute__((amdgpu_waves_per_eu(2, 2)))
void nn_mfma8(
    const ushort_t* __restrict__ qh, const ushort_t* __restrict__ xh,
    int2* __restrict__ keys, int N) {
  __shared__ __align__(1024) char smem[131072];   // 4 half-buffers x 32KB
  const int tid = threadIdx.x;
  const int l = tid & 63, w = tid >> 6;           // 8 waves
  const int wm = w >> 1, wn = w & 1;              // 4M x 2N; wave tile 64 x 128
  const int lrow = l & 15, lk8 = (l >> 4) * 8;
  const int totTiles = (N + 255) >> 8;            // 391
  const int split = (blockIdx.x + 17 * blockIdx.y) & (NSPLIT - 1);
  const int m0 = blockIdx.y * BM;
  const int T0 = (totTiles * split) >> 6;
  const int T1 = (totTiles * (split + 1)) >> 6;
  const int nStart = T0 << 8;
  const int nEnd = min(T1 << 8, N);
  const int nTiles = T1 - T0;
  const int nH = nTiles * 16;                     // 16 K-halves per 256-wide n-tile

  uint32_t K1[16], K2[16];
  #pragma unroll
  for (int s = 0; s < 16; ++s) { K1[s] = 0u; K2[s] = 0u; }

  // staging bases: waves 0-3 -> A blobs 4w..4w+3 (loop-invariant);
  // waves 4-7 -> B blobs 4(w-4)..4(w-4)+3 (recomputed per stage-tile, cached)
  size_t off4[4];
  int bCachedTile = -1;
  if (w < 4) {
    #pragma unroll
    for (int t = 0; t < 4; ++t)
      off4[t] = (size_t)(m0 + 16 * (4 * w + t) + lrow) * DIM + lk8;
  }

  auto STAGE2 = [&](int Hs, int q) {
    Hs = min(Hs, nH - 1);
    char* base = smem + (Hs & 3) * 32768;
    int k0 = (Hs & 15) * 32;
    if (w >= 4) {
      int tile = Hs >> 4;
      if (tile != bCachedTile) {
        int sn0 = nStart + (tile << 8);
        #pragma unroll
        for (int t = 0; t < 4; ++t)
          off4[t] = (size_t)min(sn0 + 16 * (4 * (w - 4) + t) + lrow, N - 1) * DIM + lk8;
        bCachedTile = tile;
      }
      #pragma unroll
      for (int t = 0; t < 2; ++t) {
        int tt = 2 * q + t;
        int b = 16 + 4 * (w - 4) + tt;
        __builtin_amdgcn_global_load_lds((const AS1 int*)(xh + off4[tt] + k0),
                                         (AS3 int*)(base + b * 1024), 16, 0, 0);
      }
    } else {
      #pragma unroll
      for (int t = 0; t < 2; ++t) {
        int tt = 2 * q + t;
        int b = 4 * w + tt;
        __builtin_amdgcn_global_load_lds((const AS1 int*)(qh + off4[tt] + k0),
                                         (AS3 int*)(base + b * 1024), 16, 0, 0);
      }
    }
  };

  // prologue: 3 halves in flight (4 loads/wave/half)
  STAGE2(0, 0); STAGE2(0, 1);
  STAGE2(1, 0); STAGE2(1, 1);
  STAGE2(2, 0); STAGE2(2, 1);

  fvec4 acc[4][8];
  const fvec4 zero4 = {0.f, 0.f, 0.f, 0.f};       // proven numeric path: bias at fold

  #pragma unroll 1
  for (int H = 0; H < nH; ++H) {
    if ((H & 15) == 0) {
      #pragma unroll
      for (int i = 0; i < 4; ++i)
        #pragma unroll
        for (int j = 0; j < 8; ++j) acc[i][j] = zero4;
    }
    const char* rb = smem + (H & 3) * 32768;

    // ---- phase 0: counted-vmcnt barrier, A(4)+B(4) reads, stage q0, 16 MFMA ----
    asm volatile("s_waitcnt vmcnt(8)\n\ts_barrier" ::: "memory");
    __builtin_amdgcn_sched_barrier(0);
    bvec8 Af[4], Bf[4];
    #pragma unroll
    for (int i = 0; i < 4; ++i)
      Af[i] = __builtin_bit_cast(bvec8, *(const ivec4*)(rb + (wm * 4 + i) * 1024 + l * 16));
    #pragma unroll
    for (int j = 0; j < 4; ++j)
      Bf[j] = __builtin_bit_cast(bvec8, *(const ivec4*)(rb + 16384 + (wn * 8 + j) * 1024 + l * 16));
    STAGE2(H + 3, 0);
    __builtin_amdgcn_s_setprio(1);
    #pragma unroll
    for (int i = 0; i < 4; ++i)
      #pragma unroll
      for (int j = 0; j < 4; ++j)
        acc[i][j] = __builtin_amdgcn_mfma_f32_16x16x32_bf16(Af[i], Bf[j], acc[i][j], 0, 0, 0);
    __builtin_amdgcn_s_setprio(0);

    // ---- phase 1: barrier, B(4) reads (A reused), stage q1, 16 MFMA ----
    __builtin_amdgcn_s_barrier();
    bvec8 Bg[4];
    #pragma unroll
    for (int j = 0; j < 4; ++j)
      Bg[j] = __builtin_bit_cast(bvec8, *(const ivec4*)(rb + 16384 + (wn * 8 + 4 + j) * 1024 + l * 16));
    STAGE2(H + 3, 1);
    __builtin_amdgcn_s_setprio(1);
    #pragma unroll
    for (int i = 0; i < 4; ++i)
      #pragma unroll
      for (int j = 0; j < 4; ++j)
        acc[i][4 + j] = __builtin_amdgcn_mfma_f32_16x16x32_bf16(Af[i], Bg[j], acc[i][4 + j], 0, 0, 0);
    __builtin_amdgcn_s_setprio(0);

    // ---- end of n-tile: branchless top-2 fold (+8 bias applied HERE, R15-proven) ----
    if ((H & 15) == 15) {
      int n0 = nStart + ((H >> 4) << 8);
      uint32_t msk[8], nb[8];
      #pragma unroll
      for (int j = 0; j < 8; ++j) {
        int n = n0 + wn * 128 + j * 16 + lrow;
        bool valid = n < nEnd;
        msk[j] = valid ? 0xFFFFF800u : 0u;
        nb[j]  = valid ? (uint32_t)(2047 - (n - nStart)) : 0u;
      }
      #pragma unroll
      for (int i = 0; i < 4; ++i)
        #pragma unroll
        for (int j = 0; j < 8; ++j)
          #pragma unroll
          for (int r = 0; r < 4; ++r) {
            int ss = i * 4 + r;
            uint32_t key = (__builtin_bit_cast(uint32_t, acc[i][j][r] + 8.0f) & msk[j]) | nb[j];
            uint32_t lo = min(K1[ss], key);
            K1[ss] = max(K1[ss], key);
            K2[ss] = max(K2[ss], lo);
          }
    }
  }

  // cross-lane top-2 merge over the 16 lanes sharing each query row
  #pragma unroll
  for (int s = 0; s < 16; ++s) {
    uint32_t k1 = K1[s], k2 = K2[s];
    #pragma unroll
    for (int off = 1; off < 16; off <<= 1) {
      uint32_t o1 = (uint32_t)__shfl_xor((int)k1, off, 64);
      uint32_t o2 = (uint32_t)__shfl_xor((int)k2, off, 64);
      uint32_t nk2 = max(min(k1, o1), max(k2, o2));
      k1 = max(k1, o1);
      k2 = nk2;
    }
    if (lrow == 0) {
      int m = m0 + wm * 64 + (s >> 2) * 16 + (l >> 4) * 4 + (s & 3);
      keys[((size_t)m * NSPLIT + split) * 2 + wn] = make_int2((int)k1, (int)k2);
    }
  }
}

// ---------- fallback (no-ws path): R13 structure, f32 on-the-fly ----------
__global__ __launch_bounds__(256)
__attribute__((amdgpu_waves_per_eu(2, 2)))
void nn_mfma_fb(
    const float* __restrict__ qf, const float* __restrict__ xf,
    const float* __restrict__ rnorm,
    int2* __restrict__ keys, int N) {
  __shared__ __align__(1024) char smem[49152];
  const int tid = threadIdx.x;
  const int l = tid & 63, wv = tid >> 6;
  const int lrow = l & 15;
  const int totTiles = (N + 255) >> 8;
  const int split = blockIdx.x;
  const int m0 = blockIdx.y * BM;
  const int nStart = ((totTiles * split) >> 6) << 8;
  const int nEnd = min(((totTiles * (split + 1)) >> 6) << 8, N);

  uint32_t K1[16], K2[16];
  #pragma unroll
  for (int s = 0; s < 16; ++s) { K1[s] = 0u; K2[s] = 0u; }
  const fvec4 zero4 = {0.f, 0.f, 0.f, 0.f};

  auto STAGE = [&](int c, int sn0, int sk0) {
    char* base = smem + c * 24576;
    #pragma unroll
    for (int u = 0; u < 6; ++u) {
      int unit = tid + 256 * u;
      if (unit < 1024) {
        int row = unit >> 2, kg = unit & 3;
        int boff_l = (row >> 4) * 1024 + kg * 256 + (row & 15) * 16;
        const float* s0 = qf + (size_t)(m0 + row) * DIM + sk0 + kg * 8;
        float4 a0 = *(const float4*)s0, a1 = *(const float4*)(s0 + 4);
        float vv[8] = {a0.x,a0.y,a0.z,a0.w,a1.x,a1.y,a1.z,a1.w};
        ivec4 hw;
        #pragma unroll
        for (int t = 0; t < 4; ++t) {
          ushort_t h0 = bf16_rne(vv[2*t]), h1 = bf16_rne(vv[2*t+1]);
          hw[t] = (int)((uint32_t)h0 | ((uint32_t)h1 << 16));
        }
        *(ivec4*)(base + boff_l) = hw;
      } else {
        int u2 = unit - 1024;
        int row = u2 >> 2, kg = u2 & 3;
        int boff_l = 16384 + (row >> 4) * 1024 + kg * 256 + (row & 15) * 16;
        int gr = min(sn0 + row, N - 1);
        float rn = rnorm[gr];
        const float* s0 = xf + (size_t)gr * DIM + sk0 + kg * 8;
        float4 a0 = *(const float4*)s0, a1 = *(const float4*)(s0 + 4);
        float vv[8] = {a0.x*rn,a0.y*rn,a0.z*rn,a0.w*rn,a1.x*rn,a1.y*rn,a1.z*rn,a1.w*rn};
        ivec4 hw;
        #pragma unroll
        for (int t = 0; t < 4; ++t) {
          ushort_t h0 = bf16_rne(vv[2*t]), h1 = bf16_rne(vv[2*t+1]);
          hw[t] = (int)((uint32_t)h0 | ((uint32_t)h1 << 16));
        }
        *(ivec4*)(base + boff_l) = hw;
      }
    }
  };

  const int nTiles = (nEnd - nStart + 127) >> 7;
  const int S = nTiles * 16;
  STAGE(0, nStart, 0);
  if (S > 1) STAGE(1 % 3, nStart, 32);
  __syncthreads();

  fvec4 acc[4][8];
  #pragma unroll 1
  for (int s = 0; s < S; ++s) {
    if ((s & 15) == 0) {
      #pragma unroll
      for (int i = 0; i < 4; ++i)
        #pragma unroll
        for (int j = 0; j < 8; ++j) acc[i][j] = zero4;
    }
    if (s + 2 < S) STAGE((s + 2) % 3, nStart + (((s + 2) >> 4) * 128), ((s + 2) & 15) * 32);
    const char* rb = smem + (s % 3) * 24576;
    bvec8 Ah[4], Bh[8];
    #pragma unroll
    for (int i = 0; i < 4; ++i)
      Ah[i] = __builtin_bit_cast(bvec8, *(const ivec4*)(rb + (wv*4 + i) * 1024 + l * 16));
    #pragma unroll
    for (int j = 0; j < 8; ++j)
      Bh[j] = __builtin_bit_cast(bvec8, *(const ivec4*)(rb + 16384 + j * 1024 + l * 16));
    #pragma unroll
    for (int i = 0; i < 4; ++i)
      #pragma unroll
      for (int j = 0; j < 8; ++j)
        acc[i][j] = __builtin_amdgcn_mfma_f32_16x16x32_bf16(Ah[i], Bh[j], acc[i][j], 0, 0, 0);
    if ((s & 15) == 15) {
      int n0 = nStart + ((s >> 4) * 128);
      uint32_t msk[8], nb[8];
      #pragma unroll
      for (int j = 0; j < 8; ++j) {
        int n = n0 + j * 16 + lrow;
        bool valid = n < nEnd;
        msk[j] = valid ? 0xFFFFF800u : 0u;
        nb[j]  = valid ? (uint32_t)(2047 - (n - nStart)) : 0u;
      }
      #pragma unroll
      for (int i = 0; i < 4; ++i)
        #pragma unroll
        for (int j = 0; j < 8; ++j)
          #pragma unroll
          for (int r = 0; r < 4; ++r) {
            int ss = i * 4 + r;
            uint32_t key = (__builtin_bit_cast(uint32_t, acc[i][j][r] + 8.0f) & msk[j]) | nb[j];
            uint32_t lo = min(K1[ss], key);
            K1[ss] = max(K1[ss], key);
            K2[ss] = max(K2[ss], lo);
          }
    }
    __syncthreads();
  }

  #pragma unroll
  for (int s = 0; s < 16; ++s) {
    uint32_t k1 = K1[s], k2 = K2[s];
    #pragma unroll
    for (int off = 1; off < 16; off <<= 1) {
      uint32_t o1 = (uint32_t)__shfl_xor((int)k1, off, 64);
      uint32_t o2 = (uint32_t)__shfl_xor((int)k2, off, 64);
      uint32_t nk2 = max(min(k1, o1), max(k2, o2));
      k1 = max(k1, o1);
      k2 = nk2;
    }
    if (lrow == 0) {
      int m = m0 + wv * 64 + (s >> 2) * 16 + (l >> 4) * 4 + (s & 3);
      keys[((size_t)m * NSPLIT + split) * 2 + 0] = make_int2((int)k1, (int)k2);
      keys[((size_t)m * NSPLIT + split) * 2 + 1] = make_int2(0, 0);
    }
  }
}

// ---------- finalize: unpack 256 candidate slots, exact f32 rescore, one-hot ----------
__global__ __launch_bounds__(256) void finalize_kernel(
    const int2* __restrict__ keys,
    const float* __restrict__ qf, const float* __restrict__ xf,
    const float* __restrict__ rnorm, const int* __restrict__ y,
    int* __restrict__ out, int N) {
  int m = blockIdx.x;
  int tid = threadIdx.x, l = tid & 63, w = tid >> 6;
  const int totTiles = (N + 255) >> 8;
  __shared__ float sv[256]; __shared__ int si[256];
  __shared__ float swm[4];
  __shared__ float swv[4]; __shared__ int swi[4];
  __shared__ int s_label;
  {
    int slot = tid >> 1;                       // split*2 + wn
    int2 kk = keys[(size_t)m * 128 + slot];
    uint32_t k = (tid & 1) ? (uint32_t)kk.y : (uint32_t)kk.x;
    float v; int idx;
    if (k == 0) { v = -FLT_MAX; idx = 0x7fffffff; }
    else {
      int sp = slot >> 1;
      int nStart = ((totTiles * sp) >> 6) << 8;
      v = __builtin_bit_cast(float, k & 0xFFFFF800u) - 8.0f;
      idx = nStart + 2047 - (int)(k & 0x7FFu);
    }
    sv[tid] = v; si[tid] = idx;
  }
  __syncthreads();
  float v = sv[tid];
  #pragma unroll
  for (int off = 1; off < 64; off <<= 1) v = fmaxf(v, __shfl_xor(v, off, 64));
  if (l == 0) swm[w] = v;
  __syncthreads();
  float svmax = fmaxf(fmaxf(swm[0], swm[1]), fmaxf(swm[2], swm[3]));
  float thresh = svmax - MARGIN;
  float bestv = -FLT_MAX; int besti = 0x7fffffff;
  for (int cc = 0; cc < 64; ++cc) {
    int c = w * 64 + cc;
    float av = sv[c]; int idx = si[c];
    if (av < thresh) continue;  // wave-uniform branch
    const float4* qp = (const float4*)(qf + (size_t)m * DIM);
    const float4* xp = (const float4*)(xf + (size_t)idx * DIM);
    float s = 0.f;
    #pragma unroll
    for (int t = 0; t < 2; ++t) {
      float4 qa = qp[l * 2 + t], xa = xp[l * 2 + t];
      s += qa.x*xa.x + qa.y*xa.y + qa.z*xa.z + qa.w*xa.w;
    }
    #pragma unroll
    for (int off = 1; off < 64; off <<= 1) s += __shfl_xor(s, off, 64);
    float ev = s * rnorm[idx];
    if (ev > bestv || (ev == bestv && idx < besti)) { bestv = ev; besti = idx; }
  }
  if (l == 0) { swv[w] = bestv; swi[w] = besti; }
  __syncthreads();
  if (tid == 0) {
    float bv = swv[0]; int bi = swi[0];
    #pragma unroll
    for (int k = 1; k < 4; ++k)
      if (swv[k] > bv || (swv[k] == bv && swi[k] < bi)) { bv = swv[k]; bi = swi[k]; }
    s_label = y[bi];
  }
  __syncthreads();
  int label = s_label;
  for (int c = tid; c < NUM_CLASSES; c += 256)
    out[(size_t)m * NUM_CLASSES + c] = (c == label) ? 1 : 0;
}

extern "C" void kernel_launch(void* const* d_in, const int* in_sizes, int n_in,
                              void* d_out, int out_size, void* d_ws, size_t ws_size,
                              hipStream_t stream) {
  const float* x = (const float*)d_in[0];   // [N, 512]
  const int*   y = (const int*)d_in[1];     // [N]
  const float* q = (const float*)d_in[2];   // [M, 512]
  int N = in_sizes[0] / DIM;                // 100000
  int M = in_sizes[2] / DIM;                // 2048
  int* out = (int*)d_out;

  // workspace layout
  size_t off = 0;
  float* rnorm = (float*)((char*)d_ws + off); off += (((size_t)N * 4 + 1023) / 1024) * 1024;
  int2* keys   = (int2*)((char*)d_ws + off);  off += (size_t)M * NSPLIT * 2 * 8;
  ushort_t* qh = (ushort_t*)((char*)d_ws + off); off += (size_t)M * DIM * 2;
  ushort_t* xh = (ushort_t*)((char*)d_ws + off); off += (size_t)N * DIM * 2;
  bool pre = (ws_size >= off);

  if (pre) {
    prep_bf16<<<(N + 3) / 4, 256, 0, stream>>>(x, rnorm, xh, N, 1);
    prep_bf16<<<(M + 3) / 4, 256, 0, stream>>>(q, nullptr, qh, M, 0);
    dim3 grid(NSPLIT, M / BM);                // 64 x 8 = 512 blocks, 2/CU
    nn_mfma8<<<grid, 512, 0, stream>>>(qh, xh, keys, N);
  } else {
    prep_bf16<<<(N + 3) / 4, 256, 0, stream>>>(x, rnorm, nullptr, N, 1);
    dim3 gridf(NSPLIT, M / BM);               // fallback: 256-thread R13 structure
    nn_mfma_fb<<<gridf, 256, 0, stream>>>(q, x, rnorm, keys, N);
  }
  finalize_kernel<<<M, 256, 0, stream>>>(keys, q, x, rnorm, y, out, N);
}

// Round 18
// 310.425 us; speedup vs baseline: 1.0760x; 1.0399x over previous
//
#include <hip/hip_runtime.h>
#include <float.h>
#include <stdint.h>

#define DIM 512
#define BM 256
#define BN 256
#define NSPLIT 64
#define NUM_CLASSES 1000
#define MARGIN 0.04f

typedef unsigned short ushort_t;
typedef __attribute__((ext_vector_type(4))) float fvec4;
typedef __attribute__((ext_vector_type(8))) __bf16 bvec8;
typedef __attribute__((ext_vector_type(4))) int ivec4;

#define AS1 __attribute__((address_space(1)))
#define AS3 __attribute__((address_space(3)))

__device__ inline ushort_t bf16_rne(float f) {
  uint32_t u = __builtin_bit_cast(uint32_t, f);
  uint32_t r = u + 0x7fffu + ((u >> 16) & 1u);
  return (ushort_t)(r >> 16);
}

// ---------- prep: rnorm + f32 -> bf16 (RNE) plane ----------
__global__ __launch_bounds__(256) void prep_bf16(
    const float* __restrict__ src, float* __restrict__ rnorm_out,
    ushort_t* __restrict__ hi, int rows, int scale) {
  int row = blockIdx.x * 4 + (threadIdx.x >> 6);
  int l = threadIdx.x & 63;
  if (row >= rows) return;
  const float4* p = (const float4*)(src + (size_t)row * DIM);
  float4 a = p[l * 2], b = p[l * 2 + 1];
  float rn = 1.0f;
  if (scale) {
    float s = a.x*a.x + a.y*a.y + a.z*a.z + a.w*a.w
            + b.x*b.x + b.y*b.y + b.z*b.z + b.w*b.w;
    #pragma unroll
    for (int off = 1; off < 64; off <<= 1) s += __shfl_xor(s, off, 64);
    rn = 1.0f / fmaxf(sqrtf(s), 1e-12f);
    if (rnorm_out && l == 0) rnorm_out[row] = rn;
  }
  if (!hi) return;
  float v[8] = {a.x*rn, a.y*rn, a.z*rn, a.w*rn, b.x*rn, b.y*rn, b.z*rn, b.w*rn};
  ivec4 hw;
  #pragma unroll
  for (int t = 0; t < 4; ++t) {
    ushort_t h0 = bf16_rne(v[2*t]), h1 = bf16_rne(v[2*t+1]);
    hw[t] = (int)((uint32_t)h0 | ((uint32_t)h1 << 16));
  }
  *(ivec4*)(hi + (size_t)row * DIM + l * 8) = hw;
}

// ---------- screen (main): 8-wave 256x256, phase schedule + tile-exact splits ----------
// R17 banked: bias MUST be applied at fold (acc init = 0) -- bias-in-init failed 2x.
// R17 miss: split=(bx+17*by) broke same-split XCD locality -> FETCH 458MB, stage
// loads at HBM latency. R18: split = (bx + 8*by) & 63:
//  (a) split%8 == bx%8 == linear_id%8 -> all 8 blocks of a split on ONE XCD (L2);
//  (b) CU pair (by, by+4) -> splits differ by 32 (same residue mod 8); the 7-tile
//      splits {9,18,27,36,45,54,63} have distinct residues mod 8 -> at most one
//      7-tile split per CU -> makespan 13 kept.
__global__ __launch_bounds__(512)
__attribute__((amdgpu_waves_per_eu(2, 2)))
void nn_mfma8(
    const ushort_t* __restrict__ qh, const ushort_t* __restrict__ xh,
    int2* __restrict__ keys, int N) {
  __shared__ __align__(1024) char smem[131072];   // 4 half-buffers x 32KB
  const int tid = threadIdx.x;
  const int l = tid & 63, w = tid >> 6;           // 8 waves
  const int wm = w >> 1, wn = w & 1;              // 4M x 2N; wave tile 64 x 128
  const int lrow = l & 15, lk8 = (l >> 4) * 8;
  const int totTiles = (N + 255) >> 8;            // 391
  const int split = (blockIdx.x + 8 * blockIdx.y) & (NSPLIT - 1);
  const int m0 = blockIdx.y * BM;
  const int T0 = (totTiles * split) >> 6;
  const int T1 = (totTiles * (split + 1)) >> 6;
  const int nStart = T0 << 8;
  const int nEnd = min(T1 << 8, N);
  const int nTiles = T1 - T0;
  const int nH = nTiles * 16;                     // 16 K-halves per 256-wide n-tile

  uint32_t K1[16], K2[16];
  #pragma unroll
  for (int s = 0; s < 16; ++s) { K1[s] = 0u; K2[s] = 0u; }

  // staging bases: waves 0-3 -> A blobs 4w..4w+3 (loop-invariant);
  // waves 4-7 -> B blobs 4(w-4)..4(w-4)+3 (recomputed per stage-tile, cached)
  size_t off4[4];
  int bCachedTile = -1;
  if (w < 4) {
    #pragma unroll
    for (int t = 0; t < 4; ++t)
      off4[t] = (size_t)(m0 + 16 * (4 * w + t) + lrow) * DIM + lk8;
  }

  auto STAGE2 = [&](int Hs, int q) {
    Hs = min(Hs, nH - 1);
    char* base = smem + (Hs & 3) * 32768;
    int k0 = (Hs & 15) * 32;
    if (w >= 4) {
      int tile = Hs >> 4;
      if (tile != bCachedTile) {
        int sn0 = nStart + (tile << 8);
        #pragma unroll
        for (int t = 0; t < 4; ++t)
          off4[t] = (size_t)min(sn0 + 16 * (4 * (w - 4) + t) + lrow, N - 1) * DIM + lk8;
        bCachedTile = tile;
      }
      #pragma unroll
      for (int t = 0; t < 2; ++t) {
        int tt = 2 * q + t;
        int b = 16 + 4 * (w - 4) + tt;
        __builtin_amdgcn_global_load_lds((const AS1 int*)(xh + off4[tt] + k0),
                                         (AS3 int*)(base + b * 1024), 16, 0, 0);
      }
    } else {
      #pragma unroll
      for (int t = 0; t < 2; ++t) {
        int tt = 2 * q + t;
        int b = 4 * w + tt;
        __builtin_amdgcn_global_load_lds((const AS1 int*)(qh + off4[tt] + k0),
                                         (AS3 int*)(base + b * 1024), 16, 0, 0);
      }
    }
  };

  // prologue: 3 halves in flight (4 loads/wave/half)
  STAGE2(0, 0); STAGE2(0, 1);
  STAGE2(1, 0); STAGE2(1, 1);
  STAGE2(2, 0); STAGE2(2, 1);

  fvec4 acc[4][8];
  const fvec4 zero4 = {0.f, 0.f, 0.f, 0.f};       // proven numeric path: bias at fold

  #pragma unroll 1
  for (int H = 0; H < nH; ++H) {
    if ((H & 15) == 0) {
      #pragma unroll
      for (int i = 0; i < 4; ++i)
        #pragma unroll
        for (int j = 0; j < 8; ++j) acc[i][j] = zero4;
    }
    const char* rb = smem + (H & 3) * 32768;

    // ---- phase 0: counted-vmcnt barrier, A(4)+B(4) reads, stage q0, 16 MFMA ----
    asm volatile("s_waitcnt vmcnt(8)\n\ts_barrier" ::: "memory");
    __builtin_amdgcn_sched_barrier(0);
    bvec8 Af[4], Bf[4];
    #pragma unroll
    for (int i = 0; i < 4; ++i)
      Af[i] = __builtin_bit_cast(bvec8, *(const ivec4*)(rb + (wm * 4 + i) * 1024 + l * 16));
    #pragma unroll
    for (int j = 0; j < 4; ++j)
      Bf[j] = __builtin_bit_cast(bvec8, *(const ivec4*)(rb + 16384 + (wn * 8 + j) * 1024 + l * 16));
    STAGE2(H + 3, 0);
    __builtin_amdgcn_s_setprio(1);
    #pragma unroll
    for (int i = 0; i < 4; ++i)
      #pragma unroll
      for (int j = 0; j < 4; ++j)
        acc[i][j] = __builtin_amdgcn_mfma_f32_16x16x32_bf16(Af[i], Bf[j], acc[i][j], 0, 0, 0);
    __builtin_amdgcn_s_setprio(0);

    // ---- phase 1: barrier, B(4) reads (A reused), stage q1, 16 MFMA ----
    __builtin_amdgcn_s_barrier();
    bvec8 Bg[4];
    #pragma unroll
    for (int j = 0; j < 4; ++j)
      Bg[j] = __builtin_bit_cast(bvec8, *(const ivec4*)(rb + 16384 + (wn * 8 + 4 + j) * 1024 + l * 16));
    STAGE2(H + 3, 1);
    __builtin_amdgcn_s_setprio(1);
    #pragma unroll
    for (int i = 0; i < 4; ++i)
      #pragma unroll
      for (int j = 0; j < 4; ++j)
        acc[i][4 + j] = __builtin_amdgcn_mfma_f32_16x16x32_bf16(Af[i], Bg[j], acc[i][4 + j], 0, 0, 0);
    __builtin_amdgcn_s_setprio(0);

    // ---- end of n-tile: branchless top-2 fold (+8 bias applied HERE) ----
    if ((H & 15) == 15) {
      int n0 = nStart + ((H >> 4) << 8);
      uint32_t msk[8], nb[8];
      #pragma unroll
      for (int j = 0; j < 8; ++j) {
        int n = n0 + wn * 128 + j * 16 + lrow;
        bool valid = n < nEnd;
        msk[j] = valid ? 0xFFFFF800u : 0u;
        nb[j]  = valid ? (uint32_t)(2047 - (n - nStart)) : 0u;
      }
      #pragma unroll
      for (int i = 0; i < 4; ++i)
        #pragma unroll
        for (int j = 0; j < 8; ++j)
          #pragma unroll
          for (int r = 0; r < 4; ++r) {
            int ss = i * 4 + r;
            uint32_t key = (__builtin_bit_cast(uint32_t, acc[i][j][r] + 8.0f) & msk[j]) | nb[j];
            uint32_t lo = min(K1[ss], key);
            K1[ss] = max(K1[ss], key);
            K2[ss] = max(K2[ss], lo);
          }
    }
  }

  // cross-lane top-2 merge over the 16 lanes sharing each query row
  #pragma unroll
  for (int s = 0; s < 16; ++s) {
    uint32_t k1 = K1[s], k2 = K2[s];
    #pragma unroll
    for (int off = 1; off < 16; off <<= 1) {
      uint32_t o1 = (uint32_t)__shfl_xor((int)k1, off, 64);
      uint32_t o2 = (uint32_t)__shfl_xor((int)k2, off, 64);
      uint32_t nk2 = max(min(k1, o1), max(k2, o2));
      k1 = max(k1, o1);
      k2 = nk2;
    }
    if (lrow == 0) {
      int m = m0 + wm * 64 + (s >> 2) * 16 + (l >> 4) * 4 + (s & 3);
      keys[((size_t)m * NSPLIT + split) * 2 + wn] = make_int2((int)k1, (int)k2);
    }
  }
}

// ---------- fallback (no-ws path): R13 structure, f32 on-the-fly ----------
__global__ __launch_bounds__(256)
__attribute__((amdgpu_waves_per_eu(2, 2)))
void nn_mfma_fb(
    const float* __restrict__ qf, const float* __restrict__ xf,
    const float* __restrict__ rnorm,
    int2* __restrict__ keys, int N) {
  __shared__ __align__(1024) char smem[49152];
  const int tid = threadIdx.x;
  const int l = tid & 63, wv = tid >> 6;
  const int lrow = l & 15;
  const int totTiles = (N + 255) >> 8;
  const int split = blockIdx.x;
  const int m0 = blockIdx.y * BM;
  const int nStart = ((totTiles * split) >> 6) << 8;
  const int nEnd = min(((totTiles * (split + 1)) >> 6) << 8, N);

  uint32_t K1[16], K2[16];
  #pragma unroll
  for (int s = 0; s < 16; ++s) { K1[s] = 0u; K2[s] = 0u; }
  const fvec4 zero4 = {0.f, 0.f, 0.f, 0.f};

  auto STAGE = [&](int c, int sn0, int sk0) {
    char* base = smem + c * 24576;
    #pragma unroll
    for (int u = 0; u < 6; ++u) {
      int unit = tid + 256 * u;
      if (unit < 1024) {
        int row = unit >> 2, kg = unit & 3;
        int boff_l = (row >> 4) * 1024 + kg * 256 + (row & 15) * 16;
        const float* s0 = qf + (size_t)(m0 + row) * DIM + sk0 + kg * 8;
        float4 a0 = *(const float4*)s0, a1 = *(const float4*)(s0 + 4);
        float vv[8] = {a0.x,a0.y,a0.z,a0.w,a1.x,a1.y,a1.z,a1.w};
        ivec4 hw;
        #pragma unroll
        for (int t = 0; t < 4; ++t) {
          ushort_t h0 = bf16_rne(vv[2*t]), h1 = bf16_rne(vv[2*t+1]);
          hw[t] = (int)((uint32_t)h0 | ((uint32_t)h1 << 16));
        }
        *(ivec4*)(base + boff_l) = hw;
      } else {
        int u2 = unit - 1024;
        int row = u2 >> 2, kg = u2 & 3;
        int boff_l = 16384 + (row >> 4) * 1024 + kg * 256 + (row & 15) * 16;
        int gr = min(sn0 + row, N - 1);
        float rn = rnorm[gr];
        const float* s0 = xf + (size_t)gr * DIM + sk0 + kg * 8;
        float4 a0 = *(const float4*)s0, a1 = *(const float4*)(s0 + 4);
        float vv[8] = {a0.x*rn,a0.y*rn,a0.z*rn,a0.w*rn,a1.x*rn,a1.y*rn,a1.z*rn,a1.w*rn};
        ivec4 hw;
        #pragma unroll
        for (int t = 0; t < 4; ++t) {
          ushort_t h0 = bf16_rne(vv[2*t]), h1 = bf16_rne(vv[2*t+1]);
          hw[t] = (int)((uint32_t)h0 | ((uint32_t)h1 << 16));
        }
        *(ivec4*)(base + boff_l) = hw;
      }
    }
  };

  const int nTiles = (nEnd - nStart + 127) >> 7;
  const int S = nTiles * 16;
  STAGE(0, nStart, 0);
  if (S > 1) STAGE(1 % 3, nStart, 32);
  __syncthreads();

  fvec4 acc[4][8];
  #pragma unroll 1
  for (int s = 0; s < S; ++s) {
    if ((s & 15) == 0) {
      #pragma unroll
      for (int i = 0; i < 4; ++i)
        #pragma unroll
        for (int j = 0; j < 8; ++j) acc[i][j] = zero4;
    }
    if (s + 2 < S) STAGE((s + 2) % 3, nStart + (((s + 2) >> 4) * 128), ((s + 2) & 15) * 32);
    const char* rb = smem + (s % 3) * 24576;
    bvec8 Ah[4], Bh[8];
    #pragma unroll
    for (int i = 0; i < 4; ++i)
      Ah[i] = __builtin_bit_cast(bvec8, *(const ivec4*)(rb + (wv*4 + i) * 1024 + l * 16));
    #pragma unroll
    for (int j = 0; j < 8; ++j)
      Bh[j] = __builtin_bit_cast(bvec8, *(const ivec4*)(rb + 16384 + j * 1024 + l * 16));
    #pragma unroll
    for (int i = 0; i < 4; ++i)
      #pragma unroll
      for (int j = 0; j < 8; ++j)
        acc[i][j] = __builtin_amdgcn_mfma_f32_16x16x32_bf16(Ah[i], Bh[j], acc[i][j], 0, 0, 0);
    if ((s & 15) == 15) {
      int n0 = nStart + ((s >> 4) * 128);
      uint32_t msk[8], nb[8];
      #pragma unroll
      for (int j = 0; j < 8; ++j) {
        int n = n0 + j * 16 + lrow;
        bool valid = n < nEnd;
        msk[j] = valid ? 0xFFFFF800u : 0u;
        nb[j]  = valid ? (uint32_t)(2047 - (n - nStart)) : 0u;
      }
      #pragma unroll
      for (int i = 0; i < 4; ++i)
        #pragma unroll
        for (int j = 0; j < 8; ++j)
          #pragma unroll
          for (int r = 0; r < 4; ++r) {
            int ss = i * 4 + r;
            uint32_t key = (__builtin_bit_cast(uint32_t, acc[i][j][r] + 8.0f) & msk[j]) | nb[j];
            uint32_t lo = min(K1[ss], key);
            K1[ss] = max(K1[ss], key);
            K2[ss] = max(K2[ss], lo);
          }
    }
    __syncthreads();
  }

  #pragma unroll
  for (int s = 0; s < 16; ++s) {
    uint32_t k1 = K1[s], k2 = K2[s];
    #pragma unroll
    for (int off = 1; off < 16; off <<= 1) {
      uint32_t o1 = (uint32_t)__shfl_xor((int)k1, off, 64);
      uint32_t o2 = (uint32_t)__shfl_xor((int)k2, off, 64);
      uint32_t nk2 = max(min(k1, o1), max(k2, o2));
      k1 = max(k1, o1);
      k2 = nk2;
    }
    if (lrow == 0) {
      int m = m0 + wv * 64 + (s >> 2) * 16 + (l >> 4) * 4 + (s & 3);
      keys[((size_t)m * NSPLIT + split) * 2 + 0] = make_int2((int)k1, (int)k2);
      keys[((size_t)m * NSPLIT + split) * 2 + 1] = make_int2(0, 0);
    }
  }
}

// ---------- finalize: unpack 256 candidate slots, exact f32 rescore, one-hot ----------
__global__ __launch_bounds__(256) void finalize_kernel(
    const int2* __restrict__ keys,
    const float* __restrict__ qf, const float* __restrict__ xf,
    const float* __restrict__ rnorm, const int* __restrict__ y,
    int* __restrict__ out, int N) {
  int m = blockIdx.x;
  int tid = threadIdx.x, l = tid & 63, w = tid >> 6;
  const int totTiles = (N + 255) >> 8;
  __shared__ float sv[256]; __shared__ int si[256];
  __shared__ float swm[4];
  __shared__ float swv[4]; __shared__ int swi[4];
  __shared__ int s_label;
  {
    int slot = tid >> 1;                       // split*2 + wn
    int2 kk = keys[(size_t)m * 128 + slot];
    uint32_t k = (tid & 1) ? (uint32_t)kk.y : (uint32_t)kk.x;
    float v; int idx;
    if (k == 0) { v = -FLT_MAX; idx = 0x7fffffff; }
    else {
      int sp = slot >> 1;
      int nStart = ((totTiles * sp) >> 6) << 8;
      v = __builtin_bit_cast(float, k & 0xFFFFF800u) - 8.0f;
      idx = nStart + 2047 - (int)(k & 0x7FFu);
    }
    sv[tid] = v; si[tid] = idx;
  }
  __syncthreads();
  float v = sv[tid];
  #pragma unroll
  for (int off = 1; off < 64; off <<= 1) v = fmaxf(v, __shfl_xor(v, off, 64));
  if (l == 0) swm[w] = v;
  __syncthreads();
  float svmax = fmaxf(fmaxf(swm[0], swm[1]), fmaxf(swm[2], swm[3]));
  float thresh = svmax - MARGIN;
  float bestv = -FLT_MAX; int besti = 0x7fffffff;
  for (int cc = 0; cc < 64; ++cc) {
    int c = w * 64 + cc;
    float av = sv[c]; int idx = si[c];
    if (av < thresh) continue;  // wave-uniform branch
    const float4* qp = (const float4*)(qf + (size_t)m * DIM);
    const float4* xp = (const float4*)(xf + (size_t)idx * DIM);
    float s = 0.f;
    #pragma unroll
    for (int t = 0; t < 2; ++t) {
      float4 qa = qp[l * 2 + t], xa = xp[l * 2 + t];
      s += qa.x*xa.x + qa.y*xa.y + qa.z*xa.z + qa.w*xa.w;
    }
    #pragma unroll
    for (int off = 1; off < 64; off <<= 1) s += __shfl_xor(s, off, 64);
    float ev = s * rnorm[idx];
    if (ev > bestv || (ev == bestv && idx < besti)) { bestv = ev; besti = idx; }
  }
  if (l == 0) { swv[w] = bestv; swi[w] = besti; }
  __syncthreads();
  if (tid == 0) {
    float bv = swv[0]; int bi = swi[0];
    #pragma unroll
    for (int k = 1; k < 4; ++k)
      if (swv[k] > bv || (swv[k] == bv && swi[k] < bi)) { bv = swv[k]; bi = swi[k]; }
    s_label = y[bi];
  }
  __syncthreads();
  int label = s_label;
  for (int c = tid; c < NUM_CLASSES; c += 256)
    out[(size_t)m * NUM_CLASSES + c] = (c == label) ? 1 : 0;
}

extern "C" void kernel_launch(void* const* d_in, const int* in_sizes, int n_in,
                              void* d_out, int out_size, void* d_ws, size_t ws_size,
                              hipStream_t stream) {
  const float* x = (const float*)d_in[0];   // [N, 512]
  const int*   y = (const int*)d_in[1];     // [N]
  const float* q = (const float*)d_in[2];   // [M, 512]
  int N = in_sizes[0] / DIM;                // 100000
  int M = in_sizes[2] / DIM;                // 2048
  int* out = (int*)d_out;

  // workspace layout
  size_t off = 0;
  float* rnorm = (float*)((char*)d_ws + off); off += (((size_t)N * 4 + 1023) / 1024) * 1024;
  int2* keys   = (int2*)((char*)d_ws + off);  off += (size_t)M * NSPLIT * 2 * 8;
  ushort_t* qh = (ushort_t*)((char*)d_ws + off); off += (size_t)M * DIM * 2;
  ushort_t* xh = (ushort_t*)((char*)d_ws + off); off += (size_t)N * DIM * 2;
  bool pre = (ws_size >= off);

  if (pre) {
    prep_bf16<<<(N + 3) / 4, 256, 0, stream>>>(x, rnorm, xh, N, 1);
    prep_bf16<<<(M + 3) / 4, 256, 0, stream>>>(q, nullptr, qh, M, 0);
    dim3 grid(NSPLIT, M / BM);                // 64 x 8 = 512 blocks, 2/CU
    nn_mfma8<<<grid, 512, 0, stream>>>(qh, xh, keys, N);
  } else {
    prep_bf16<<<(N + 3) / 4, 256, 0, stream>>>(x, rnorm, nullptr, N, 1);
    dim3 gridf(NSPLIT, M / BM);               // fallback: 256-thread R13 structure
    nn_mfma_fb<<<gridf, 256, 0, stream>>>(q, x, rnorm, keys, N);
  }
  finalize_kernel<<<M, 256, 0, stream>>>(keys, q, x, rnorm, y, out, N);
}

// Round 19
// 270.073 us; speedup vs baseline: 1.2368x; 1.1494x over previous
//
#include <hip/hip_runtime.h>
#include <float.h>
#include <stdint.h>

#define DIM 512
#define BM 256
#define BN 256
#define NSPLIT 64
#define NUM_CLASSES 1000
#define MARGIN 0.5f   // fp8 screen: dot sigma ~0.05 -> 10-sigma rescore margin

typedef unsigned short ushort_t;
typedef __attribute__((ext_vector_type(4))) float fvec4;
typedef __attribute__((ext_vector_type(8))) __bf16 bvec8;
typedef __attribute__((ext_vector_type(4))) int ivec4;

#define AS1 __attribute__((address_space(1)))
#define AS3 __attribute__((address_space(3)))

__device__ inline ushort_t bf16_rne(float f) {
  uint32_t u = __builtin_bit_cast(uint32_t, f);
  uint32_t r = u + 0x7fffu + ((u >> 16) & 1u);
  return (ushort_t)(r >> 16);
}

// ---------- prep: rnorm + f32 -> fp8 e4m3 BLOB-format array ----------
// Blob = 16 rows x 32 k of fp8 (512B), interior byte(r,k) = (k>>3)*128 + r*8 + (k&7)
// Array layout: [row>>8][kchunk 0..15][rowgrp 0..15][512B]  (pre-swizzled global:
// staging then needs only contiguous 1KB global_load_lds -- m173 pattern).
// Thread = (row, kc); 16 lanes share a row (contiguous) -> shfl_xor norm reduce.
__global__ __launch_bounds__(256) void prep_fp8(
    const float* __restrict__ src, float* __restrict__ rnorm_out,
    unsigned char* __restrict__ dst, int rows, int padRows, int scale) {
  int idx = blockIdx.x * 256 + threadIdx.x;
  if (idx >= padRows * 16) return;
  int row = idx >> 4, kc = idx & 15;
  int srow = min(row, rows - 1);             // pad rows replicate last row
  const float* s0 = src + (size_t)srow * DIM + kc * 32;
  float v[32];
  #pragma unroll
  for (int t = 0; t < 8; ++t) {
    float4 a = *(const float4*)(s0 + t * 4);
    v[4*t] = a.x; v[4*t+1] = a.y; v[4*t+2] = a.z; v[4*t+3] = a.w;
  }
  float rn = 1.0f;
  if (scale) {
    float s = 0.f;
    #pragma unroll
    for (int t = 0; t < 32; ++t) s += v[t] * v[t];
    #pragma unroll
    for (int off = 1; off < 16; off <<= 1) s += __shfl_xor(s, off, 64);
    rn = 1.0f / fmaxf(sqrtf(s), 1e-12f);
    if (rnorm_out && kc == 0 && row < rows) rnorm_out[row] = rn;
  }
  unsigned char* blob = dst + (((size_t)(row >> 8) * 16 + kc) * 16 + ((row >> 4) & 15)) * 512;
  int rr = row & 15;
  #pragma unroll
  for (int g = 0; g < 4; ++g) {
    int w0 = 0, w1 = 0;
    w0 = __builtin_amdgcn_cvt_pk_fp8_f32(v[8*g+0]*rn, v[8*g+1]*rn, w0, false);
    w0 = __builtin_amdgcn_cvt_pk_fp8_f32(v[8*g+2]*rn, v[8*g+3]*rn, w0, true);
    w1 = __builtin_amdgcn_cvt_pk_fp8_f32(v[8*g+4]*rn, v[8*g+5]*rn, w1, false);
    w1 = __builtin_amdgcn_cvt_pk_fp8_f32(v[8*g+6]*rn, v[8*g+7]*rn, w1, true);
    *(int2*)(blob + g * 128 + rr * 8) = make_int2(w0, w1);
  }
}

// ---------- screen (main): 8-wave 256x256, fp8 MFMA, R18 schedule ----------
// fp8 e4m3 non-scaled = bf16 MFMA rate, but HALVES: LDS traffic (ds_read_b64),
// stage bytes (2 x 1KB loads/wave/half), buffer size (16KB/half, 4 bufs = 64KB).
// vmcnt(4): 2 loads/wave/half x 2 halves in flight (counted, never 0 in-loop).
// Banked rules: +8 bias at FOLD only (acc init 0 -- bias-in-init failed 2x);
// split=(bx+8*by)&63 (XCD locality + makespan-13); tile-exact variable splits.
// A/B within-lane k-permutation (if any) cancels: same layout both operands.
__global__ __launch_bounds__(512)
__attribute__((amdgpu_waves_per_eu(2, 2)))
void nn_mfma8(
    const unsigned char* __restrict__ qb, const unsigned char* __restrict__ xb,
    int2* __restrict__ keys, int N) {
  __shared__ __align__(1024) char smem[65536];    // 4 half-buffers x 16KB
  const int tid = threadIdx.x;
  const int l = tid & 63, w = tid >> 6;           // 8 waves
  const int wm = w >> 1, wn = w & 1;              // 4M x 2N; wave tile 64 x 128
  const int lrow = l & 15;
  const int totTiles = (N + 255) >> 8;            // 391
  const int split = (blockIdx.x + 8 * blockIdx.y) & (NSPLIT - 1);
  const int mb = blockIdx.y;
  const int m0 = mb * BM;
  const int T0 = (totTiles * split) >> 6;
  const int T1 = (totTiles * (split + 1)) >> 6;
  const int nStart = T0 << 8;
  const int nEnd = min(T1 << 8, N);
  const int nTiles = T1 - T0;
  const int nH = nTiles * 16;

  uint32_t K1[16], K2[16];
  #pragma unroll
  for (int s = 0; s < 16; ++s) { K1[s] = 0u; K2[s] = 0u; }

  // stage: one contiguous 1KB load per (wave, q): q=0 -> A rowgrps {2w,2w+1},
  // q=1 -> B rowgrps {2w,2w+1}. Blob arrays are pre-swizzled -> linear src.
  auto STAGE2 = [&](int Hs, int q) {
    Hs = min(Hs, nH - 1);
    char* base = smem + (Hs & 3) * 16384;
    int kc = Hs & 15;
    const unsigned char* src;
    char* dstbase;
    if (q == 0) {
      src = qb + (((size_t)mb * 16 + kc) * 16 + 2 * w) * 512;
      dstbase = base + w * 1024;
    } else {
      int T = T0 + (Hs >> 4);
      src = xb + (((size_t)T * 16 + kc) * 16 + 2 * w) * 512;
      dstbase = base + 8192 + w * 1024;
    }
    __builtin_amdgcn_global_load_lds((const AS1 int*)(src + l * 16), (AS3 int*)dstbase, 16, 0, 0);
  };

  // prologue: 3 halves in flight (2 loads/wave/half)
  STAGE2(0, 0); STAGE2(0, 1);
  STAGE2(1, 0); STAGE2(1, 1);
  STAGE2(2, 0); STAGE2(2, 1);

  fvec4 acc[4][8];
  const fvec4 zero4 = {0.f, 0.f, 0.f, 0.f};       // bias at fold, NOT here

  #pragma unroll 1
  for (int H = 0; H < nH; ++H) {
    if ((H & 15) == 0) {
      #pragma unroll
      for (int i = 0; i < 4; ++i)
        #pragma unroll
        for (int j = 0; j < 8; ++j) acc[i][j] = zero4;
    }
    const char* rb = smem + (H & 3) * 16384;

    // ---- phase 0: counted-vmcnt barrier, A(4)+B(4) b64 reads, stage q0, 16 MFMA ----
    asm volatile("s_waitcnt vmcnt(4)\n\ts_barrier" ::: "memory");
    __builtin_amdgcn_sched_barrier(0);
    long Af[4], Bf[4];
    #pragma unroll
    for (int i = 0; i < 4; ++i)
      Af[i] = *(const long*)(rb + (wm * 4 + i) * 512 + l * 8);
    #pragma unroll
    for (int j = 0; j < 4; ++j)
      Bf[j] = *(const long*)(rb + 8192 + (wn * 8 + j) * 512 + l * 8);
    STAGE2(H + 3, 0);
    __builtin_amdgcn_s_setprio(1);
    #pragma unroll
    for (int i = 0; i < 4; ++i)
      #pragma unroll
      for (int j = 0; j < 4; ++j)
        acc[i][j] = __builtin_amdgcn_mfma_f32_16x16x32_fp8_fp8(Af[i], Bf[j], acc[i][j], 0, 0, 0);
    __builtin_amdgcn_s_setprio(0);

    // ---- phase 1: barrier, B(4) reads (A reused), stage q1, 16 MFMA ----
    __builtin_amdgcn_s_barrier();
    long Bg[4];
    #pragma unroll
    for (int j = 0; j < 4; ++j)
      Bg[j] = *(const long*)(rb + 8192 + (wn * 8 + 4 + j) * 512 + l * 8);
    STAGE2(H + 3, 1);
    __builtin_amdgcn_s_setprio(1);
    #pragma unroll
    for (int i = 0; i < 4; ++i)
      #pragma unroll
      for (int j = 0; j < 4; ++j)
        acc[i][4 + j] = __builtin_amdgcn_mfma_f32_16x16x32_fp8_fp8(Af[i], Bg[j], acc[i][4 + j], 0, 0, 0);
    __builtin_amdgcn_s_setprio(0);

    // ---- end of n-tile: branchless top-2 fold (+8 bias applied HERE) ----
    if ((H & 15) == 15) {
      int n0 = nStart + ((H >> 4) << 8);
      uint32_t msk[8], nb[8];
      #pragma unroll
      for (int j = 0; j < 8; ++j) {
        int n = n0 + wn * 128 + j * 16 + lrow;
        bool valid = n < nEnd;
        msk[j] = valid ? 0xFFFFF800u : 0u;
        nb[j]  = valid ? (uint32_t)(2047 - (n - nStart)) : 0u;
      }
      #pragma unroll
      for (int i = 0; i < 4; ++i)
        #pragma unroll
        for (int j = 0; j < 8; ++j)
          #pragma unroll
          for (int r = 0; r < 4; ++r) {
            int ss = i * 4 + r;
            uint32_t key = (__builtin_bit_cast(uint32_t, acc[i][j][r] + 8.0f) & msk[j]) | nb[j];
            uint32_t lo = min(K1[ss], key);
            K1[ss] = max(K1[ss], key);
            K2[ss] = max(K2[ss], lo);
          }
    }
  }

  // cross-lane top-2 merge over the 16 lanes sharing each query row
  #pragma unroll
  for (int s = 0; s < 16; ++s) {
    uint32_t k1 = K1[s], k2 = K2[s];
    #pragma unroll
    for (int off = 1; off < 16; off <<= 1) {
      uint32_t o1 = (uint32_t)__shfl_xor((int)k1, off, 64);
      uint32_t o2 = (uint32_t)__shfl_xor((int)k2, off, 64);
      uint32_t nk2 = max(min(k1, o1), max(k2, o2));
      k1 = max(k1, o1);
      k2 = nk2;
    }
    if (lrow == 0) {
      int m = m0 + wm * 64 + (s >> 2) * 16 + (l >> 4) * 4 + (s & 3);
      keys[((size_t)m * NSPLIT + split) * 2 + wn] = make_int2((int)k1, (int)k2);
    }
  }
}

// ---------- fallback (no-ws path): R18 structure, f32 -> bf16 on-the-fly ----------
__global__ __launch_bounds__(256)
__attribute__((amdgpu_waves_per_eu(2, 2)))
void nn_mfma_fb(
    const float* __restrict__ qf, const float* __restrict__ xf,
    const float* __restrict__ rnorm,
    int2* __restrict__ keys, int N) {
  __shared__ __align__(1024) char smem[49152];
  const int tid = threadIdx.x;
  const int l = tid & 63, wv = tid >> 6;
  const int lrow = l & 15;
  const int totTiles = (N + 255) >> 8;
  const int split = blockIdx.x;
  const int m0 = blockIdx.y * BM;
  const int nStart = ((totTiles * split) >> 6) << 8;
  const int nEnd = min(((totTiles * (split + 1)) >> 6) << 8, N);

  uint32_t K1[16], K2[16];
  #pragma unroll
  for (int s = 0; s < 16; ++s) { K1[s] = 0u; K2[s] = 0u; }
  const fvec4 zero4 = {0.f, 0.f, 0.f, 0.f};

  auto STAGE = [&](int c, int sn0, int sk0) {
    char* base = smem + c * 24576;
    #pragma unroll
    for (int u = 0; u < 6; ++u) {
      int unit = tid + 256 * u;
      if (unit < 1024) {
        int row = unit >> 2, kg = unit & 3;
        int boff_l = (row >> 4) * 1024 + kg * 256 + (row & 15) * 16;
        const float* s0 = qf + (size_t)(m0 + row) * DIM + sk0 + kg * 8;
        float4 a0 = *(const float4*)s0, a1 = *(const float4*)(s0 + 4);
        float vv[8] = {a0.x,a0.y,a0.z,a0.w,a1.x,a1.y,a1.z,a1.w};
        ivec4 hw;
        #pragma unroll
        for (int t = 0; t < 4; ++t) {
          ushort_t h0 = bf16_rne(vv[2*t]), h1 = bf16_rne(vv[2*t+1]);
          hw[t] = (int)((uint32_t)h0 | ((uint32_t)h1 << 16));
        }
        *(ivec4*)(base + boff_l) = hw;
      } else {
        int u2 = unit - 1024;
        int row = u2 >> 2, kg = u2 & 3;
        int boff_l = 16384 + (row >> 4) * 1024 + kg * 256 + (row & 15) * 16;
        int gr = min(sn0 + row, N - 1);
        float rn = rnorm[gr];
        const float* s0 = xf + (size_t)gr * DIM + sk0 + kg * 8;
        float4 a0 = *(const float4*)s0, a1 = *(const float4*)(s0 + 4);
        float vv[8] = {a0.x*rn,a0.y*rn,a0.z*rn,a0.w*rn,a1.x*rn,a1.y*rn,a1.z*rn,a1.w*rn};
        ivec4 hw;
        #pragma unroll
        for (int t = 0; t < 4; ++t) {
          ushort_t h0 = bf16_rne(vv[2*t]), h1 = bf16_rne(vv[2*t+1]);
          hw[t] = (int)((uint32_t)h0 | ((uint32_t)h1 << 16));
        }
        *(ivec4*)(base + boff_l) = hw;
      }
    }
  };

  const int nTiles = (nEnd - nStart + 127) >> 7;
  const int S = nTiles * 16;
  STAGE(0, nStart, 0);
  if (S > 1) STAGE(1 % 3, nStart, 32);
  __syncthreads();

  fvec4 acc[4][8];
  #pragma unroll 1
  for (int s = 0; s < S; ++s) {
    if ((s & 15) == 0) {
      #pragma unroll
      for (int i = 0; i < 4; ++i)
        #pragma unroll
        for (int j = 0; j < 8; ++j) acc[i][j] = zero4;
    }
    if (s + 2 < S) STAGE((s + 2) % 3, nStart + (((s + 2) >> 4) * 128), ((s + 2) & 15) * 32);
    const char* rb = smem + (s % 3) * 24576;
    bvec8 Ah[4], Bh[8];
    #pragma unroll
    for (int i = 0; i < 4; ++i)
      Ah[i] = __builtin_bit_cast(bvec8, *(const ivec4*)(rb + (wv*4 + i) * 1024 + l * 16));
    #pragma unroll
    for (int j = 0; j < 8; ++j)
      Bh[j] = __builtin_bit_cast(bvec8, *(const ivec4*)(rb + 16384 + j * 1024 + l * 16));
    #pragma unroll
    for (int i = 0; i < 4; ++i)
      #pragma unroll
      for (int j = 0; j < 8; ++j)
        acc[i][j] = __builtin_amdgcn_mfma_f32_16x16x32_bf16(Ah[i], Bh[j], acc[i][j], 0, 0, 0);
    if ((s & 15) == 15) {
      int n0 = nStart + ((s >> 4) * 128);
      uint32_t msk[8], nb[8];
      #pragma unroll
      for (int j = 0; j < 8; ++j) {
        int n = n0 + j * 16 + lrow;
        bool valid = n < nEnd;
        msk[j] = valid ? 0xFFFFF800u : 0u;
        nb[j]  = valid ? (uint32_t)(2047 - (n - nStart)) : 0u;
      }
      #pragma unroll
      for (int i = 0; i < 4; ++i)
        #pragma unroll
        for (int j = 0; j < 8; ++j)
          #pragma unroll
          for (int r = 0; r < 4; ++r) {
            int ss = i * 4 + r;
            uint32_t key = (__builtin_bit_cast(uint32_t, acc[i][j][r] + 8.0f) & msk[j]) | nb[j];
            uint32_t lo = min(K1[ss], key);
            K1[ss] = max(K1[ss], key);
            K2[ss] = max(K2[ss], lo);
          }
    }
    __syncthreads();
  }

  #pragma unroll
  for (int s = 0; s < 16; ++s) {
    uint32_t k1 = K1[s], k2 = K2[s];
    #pragma unroll
    for (int off = 1; off < 16; off <<= 1) {
      uint32_t o1 = (uint32_t)__shfl_xor((int)k1, off, 64);
      uint32_t o2 = (uint32_t)__shfl_xor((int)k2, off, 64);
      uint32_t nk2 = max(min(k1, o1), max(k2, o2));
      k1 = max(k1, o1);
      k2 = nk2;
    }
    if (lrow == 0) {
      int m = m0 + wv * 64 + (s >> 2) * 16 + (l >> 4) * 4 + (s & 3);
      keys[((size_t)m * NSPLIT + split) * 2 + 0] = make_int2((int)k1, (int)k2);
      keys[((size_t)m * NSPLIT + split) * 2 + 1] = make_int2(0, 0);
    }
  }
}

// ---------- finalize: unpack 256 candidate slots, exact f32 rescore, one-hot ----------
__global__ __launch_bounds__(256) void finalize_kernel(
    const int2* __restrict__ keys,
    const float* __restrict__ qf, const float* __restrict__ xf,
    const float* __restrict__ rnorm, const int* __restrict__ y,
    int* __restrict__ out, int N) {
  int m = blockIdx.x;
  int tid = threadIdx.x, l = tid & 63, w = tid >> 6;
  const int totTiles = (N + 255) >> 8;
  __shared__ float sv[256]; __shared__ int si[256];
  __shared__ float swm[4];
  __shared__ float swv[4]; __shared__ int swi[4];
  __shared__ int s_label;
  {
    int slot = tid >> 1;                       // split*2 + wn
    int2 kk = keys[(size_t)m * 128 + slot];
    uint32_t k = (tid & 1) ? (uint32_t)kk.y : (uint32_t)kk.x;
    float v; int idx;
    if (k == 0) { v = -FLT_MAX; idx = 0x7fffffff; }
    else {
      int sp = slot >> 1;
      int nStart = ((totTiles * sp) >> 6) << 8;
      v = __builtin_bit_cast(float, k & 0xFFFFF800u) - 8.0f;
      idx = nStart + 2047 - (int)(k & 0x7FFu);
    }
    sv[tid] = v; si[tid] = idx;
  }
  __syncthreads();
  float v = sv[tid];
  #pragma unroll
  for (int off = 1; off < 64; off <<= 1) v = fmaxf(v, __shfl_xor(v, off, 64));
  if (l == 0) swm[w] = v;
  __syncthreads();
  float svmax = fmaxf(fmaxf(swm[0], swm[1]), fmaxf(swm[2], swm[3]));
  float thresh = svmax - MARGIN;
  float bestv = -FLT_MAX; int besti = 0x7fffffff;
  for (int cc = 0; cc < 64; ++cc) {
    int c = w * 64 + cc;
    float av = sv[c]; int idx = si[c];
    if (av < thresh) continue;  // wave-uniform branch
    const float4* qp = (const float4*)(qf + (size_t)m * DIM);
    const float4* xp = (const float4*)(xf + (size_t)idx * DIM);
    float s = 0.f;
    #pragma unroll
    for (int t = 0; t < 2; ++t) {
      float4 qa = qp[l * 2 + t], xa = xp[l * 2 + t];
      s += qa.x*xa.x + qa.y*xa.y + qa.z*xa.z + qa.w*xa.w;
    }
    #pragma unroll
    for (int off = 1; off < 64; off <<= 1) s += __shfl_xor(s, off, 64);
    float ev = s * rnorm[idx];
    if (ev > bestv || (ev == bestv && idx < besti)) { bestv = ev; besti = idx; }
  }
  if (l == 0) { swv[w] = bestv; swi[w] = besti; }
  __syncthreads();
  if (tid == 0) {
    float bv = swv[0]; int bi = swi[0];
    #pragma unroll
    for (int k = 1; k < 4; ++k)
      if (swv[k] > bv || (swv[k] == bv && swi[k] < bi)) { bv = swv[k]; bi = swi[k]; }
    s_label = y[bi];
  }
  __syncthreads();
  int label = s_label;
  for (int c = tid; c < NUM_CLASSES; c += 256)
    out[(size_t)m * NUM_CLASSES + c] = (c == label) ? 1 : 0;
}

extern "C" void kernel_launch(void* const* d_in, const int* in_sizes, int n_in,
                              void* d_out, int out_size, void* d_ws, size_t ws_size,
                              hipStream_t stream) {
  const float* x = (const float*)d_in[0];   // [N, 512]
  const int*   y = (const int*)d_in[1];     // [N]
  const float* q = (const float*)d_in[2];   // [M, 512]
  int N = in_sizes[0] / DIM;                // 100000
  int M = in_sizes[2] / DIM;                // 2048
  int* out = (int*)d_out;
  int totTiles = (N + 255) >> 8;            // 391
  int padN = totTiles << 8;                 // 100096

  // workspace layout (fp8 blob arrays: ~55MB total)
  size_t off = 0;
  float* rnorm = (float*)((char*)d_ws + off); off += (((size_t)N * 4 + 1023) / 1024) * 1024;
  int2* keys   = (int2*)((char*)d_ws + off);  off += (size_t)M * NSPLIT * 2 * 8;
  unsigned char* qb8 = (unsigned char*)d_ws + off; off += (size_t)M * DIM;
  unsigned char* xb8 = (unsigned char*)d_ws + off; off += (size_t)padN * DIM;
  bool pre = (ws_size >= off);

  if (pre) {
    prep_fp8<<<(padN * 16 + 255) / 256, 256, 0, stream>>>(x, rnorm, xb8, N, padN, 1);
    prep_fp8<<<(M * 16 + 255) / 256, 256, 0, stream>>>(q, nullptr, qb8, M, M, 0);
    dim3 grid(NSPLIT, M / BM);                // 64 x 8 = 512 blocks
    nn_mfma8<<<grid, 512, 0, stream>>>(qb8, xb8, keys, N);
  } else {
    prep_fp8<<<(N * 16 + 255) / 256, 256, 0, stream>>>(x, rnorm, nullptr, N, N, 1);
    dim3 gridf(NSPLIT, M / BM);               // fallback: bf16 on-the-fly
    nn_mfma_fb<<<gridf, 256, 0, stream>>>(q, x, rnorm, keys, N);
  }
  finalize_kernel<<<M, 256, 0, stream>>>(keys, q, x, rnorm, y, out, N);
}

// Round 20
// 242.296 us; speedup vs baseline: 1.3786x; 1.1146x over previous
//
#include <hip/hip_runtime.h>
#include <float.h>
#include <stdint.h>

#define DIM 512
#define BM 256   // fallback geometry only; main kernel uses 128x256 literals
#define NSPLIT 64
#define NUM_CLASSES 1000
#define MARGIN 0.5f   // fp8 screen: dot sigma ~0.05 -> 10-sigma rescore margin

typedef unsigned short ushort_t;
typedef __attribute__((ext_vector_type(4))) float fvec4;
typedef __attribute__((ext_vector_type(8))) __bf16 bvec8;
typedef __attribute__((ext_vector_type(4))) int ivec4;

#define AS1 __attribute__((address_space(1)))
#define AS3 __attribute__((address_space(3)))

__device__ inline ushort_t bf16_rne(float f) {
  uint32_t u = __builtin_bit_cast(uint32_t, f);
  uint32_t r = u + 0x7fffu + ((u >> 16) & 1u);
  return (ushort_t)(r >> 16);
}

// ---------- prep: rnorm + f32 -> fp8 e4m3 BLOB-format array ----------
// Blob = 16 rows x 32 k of fp8 (512B), interior byte(r,k) = (k>>3)*128 + r*8 + (k&7)
// Array layout: [row>>8][kchunk 0..15][rowgrp 0..15][512B]
__global__ __launch_bounds__(256) void prep_fp8(
    const float* __restrict__ src, float* __restrict__ rnorm_out,
    unsigned char* __restrict__ dst, int rows, int padRows, int scale) {
  int idx = blockIdx.x * 256 + threadIdx.x;
  if (idx >= padRows * 16) return;
  int row = idx >> 4, kc = idx & 15;
  int srow = min(row, rows - 1);             // pad rows replicate last row
  const float* s0 = src + (size_t)srow * DIM + kc * 32;
  float v[32];
  #pragma unroll
  for (int t = 0; t < 8; ++t) {
    float4 a = *(const float4*)(s0 + t * 4);
    v[4*t] = a.x; v[4*t+1] = a.y; v[4*t+2] = a.z; v[4*t+3] = a.w;
  }
  float rn = 1.0f;
  if (scale) {
    float s = 0.f;
    #pragma unroll
    for (int t = 0; t < 32; ++t) s += v[t] * v[t];
    #pragma unroll
    for (int off = 1; off < 16; off <<= 1) s += __shfl_xor(s, off, 64);
    rn = 1.0f / fmaxf(sqrtf(s), 1e-12f);
    if (rnorm_out && kc == 0 && row < rows) rnorm_out[row] = rn;
  }
  unsigned char* blob = dst + (((size_t)(row >> 8) * 16 + kc) * 16 + ((row >> 4) & 15)) * 512;
  int rr = row & 15;
  #pragma unroll
  for (int g = 0; g < 4; ++g) {
    int w0 = 0, w1 = 0;
    w0 = __builtin_amdgcn_cvt_pk_fp8_f32(v[8*g+0]*rn, v[8*g+1]*rn, w0, false);
    w0 = __builtin_amdgcn_cvt_pk_fp8_f32(v[8*g+2]*rn, v[8*g+3]*rn, w0, true);
    w1 = __builtin_amdgcn_cvt_pk_fp8_f32(v[8*g+4]*rn, v[8*g+5]*rn, w1, false);
    w1 = __builtin_amdgcn_cvt_pk_fp8_f32(v[8*g+6]*rn, v[8*g+7]*rn, w1, true);
    *(int2*)(blob + g * 128 + rr * 8) = make_int2(w0, w1);
  }
}

// ---------- screen (main): 4-wave 128x256 blocks, fp8 MFMA, 2 blocks/CU ----------
// R19 diagnosis: 512-thread block + 2-wave/SIMD reg cap -> ONE barrier domain per
// CU -> ~50% stall with no independent wave stream to fill it. R20: 256-thread
// blocks (4 waves, 2Mx2N, wave tile 64x128 unchanged), LDS 48KB -> TWO independent
// blocks co-resident per CU; one block's MFMA fills the other's barrier drain
// (m114 overlap). Staging 3x1KB loads/wave/half, counted vmcnt(6) (2 halves in
// flight). Banked rules: bias at FOLD only; split=(bx+8*by)&63 (XCD locality);
// tile-exact splits; clamp-idempotent tail stages.
__global__ __launch_bounds__(256)
__attribute__((amdgpu_waves_per_eu(2, 2)))
void nn_mfma8(
    const unsigned char* __restrict__ qb, const unsigned char* __restrict__ xb,
    int2* __restrict__ keys, int N) {
  __shared__ __align__(1024) char smem[49152];    // 4 half-buffers x 12KB (A 4K | B 8K)
  const int tid = threadIdx.x;
  const int l = tid & 63, w = tid >> 6;           // 4 waves
  const int wm = w >> 1, wn = w & 1;              // 2M x 2N; wave tile 64 x 128
  const int lrow = l & 15;
  const int totTiles = (N + 255) >> 8;            // 391
  const int split = (blockIdx.x + 8 * blockIdx.y) & (NSPLIT - 1);
  const int mb = blockIdx.y;                      // 16 m-blocks of 128 rows
  const int m0 = mb * 128;
  const int T0 = (totTiles * split) >> 6;
  const int T1 = (totTiles * (split + 1)) >> 6;
  const int nStart = T0 << 8;
  const int nEnd = min(T1 << 8, N);
  const int nTiles = T1 - T0;
  const int nH = nTiles * 16;

  uint32_t K1[16], K2[16];
  #pragma unroll
  for (int s = 0; s < 16; ++s) { K1[s] = 0u; K2[s] = 0u; }

  // A source base (loop-invariant): rowgrp (mb&1)*8 + 2w of 256-row group mb>>1
  const unsigned char* srcA0 = qb + (((size_t)(mb >> 1) * 16) * 16 + (mb & 1) * 8 + 2 * w) * 512;

  // stage part p of half Hs: p0 = A-kb (rowgrps 2w,2w+1); p1 = B-kb lo (2w,2w+1);
  // p2 = B-kb hi (2w+8,2w+9). Each is one contiguous 1KB global_load_lds.
  auto STAGE3 = [&](int Hs, int p) {
    Hs = min(Hs, nH - 1);
    char* base = smem + (Hs & 3) * 12288;
    int kc = Hs & 15;
    if (p == 0) {
      const unsigned char* src = srcA0 + (size_t)kc * 16 * 512;
      __builtin_amdgcn_global_load_lds((const AS1 int*)(src + l * 16),
                                       (AS3 int*)(base + w * 1024), 16, 0, 0);
    } else {
      int T = T0 + (Hs >> 4);
      int g = 2 * w + (p == 2 ? 8 : 0);
      const unsigned char* src = xb + (((size_t)T * 16 + kc) * 16 + g) * 512;
      __builtin_amdgcn_global_load_lds((const AS1 int*)(src + l * 16),
                                       (AS3 int*)(base + 4096 + g * 512), 16, 0, 0);
    }
  };

  // prologue: 3 halves in flight (3 loads/wave/half)
  STAGE3(0, 0); STAGE3(0, 1); STAGE3(0, 2);
  STAGE3(1, 0); STAGE3(1, 1); STAGE3(1, 2);
  STAGE3(2, 0); STAGE3(2, 1); STAGE3(2, 2);

  fvec4 acc[4][8];
  const fvec4 zero4 = {0.f, 0.f, 0.f, 0.f};       // bias at fold, NOT here

  #pragma unroll 1
  for (int H = 0; H < nH; ++H) {
    if ((H & 15) == 0) {
      #pragma unroll
      for (int i = 0; i < 4; ++i)
        #pragma unroll
        for (int j = 0; j < 8; ++j) acc[i][j] = zero4;
    }
    const char* rb = smem + (H & 3) * 12288;

    // ---- phase 0: counted-vmcnt barrier, A(4)+B(4) b64 reads, stage p0+p1, 16 MFMA ----
    asm volatile("s_waitcnt vmcnt(6)\n\ts_barrier" ::: "memory");
    __builtin_amdgcn_sched_barrier(0);
    long Af[4], Bf[4];
    #pragma unroll
    for (int i = 0; i < 4; ++i)
      Af[i] = *(const long*)(rb + (wm * 4 + i) * 512 + l * 8);
    #pragma unroll
    for (int j = 0; j < 4; ++j)
      Bf[j] = *(const long*)(rb + 4096 + (wn * 8 + j) * 512 + l * 8);
    STAGE3(H + 3, 0);
    STAGE3(H + 3, 1);
    __builtin_amdgcn_s_setprio(1);
    #pragma unroll
    for (int i = 0; i < 4; ++i)
      #pragma unroll
      for (int j = 0; j < 4; ++j)
        acc[i][j] = __builtin_amdgcn_mfma_f32_16x16x32_fp8_fp8(Af[i], Bf[j], acc[i][j], 0, 0, 0);
    __builtin_amdgcn_s_setprio(0);

    // ---- phase 1: barrier, B(4) reads (A reused), stage p2, 16 MFMA ----
    __builtin_amdgcn_s_barrier();
    long Bg[4];
    #pragma unroll
    for (int j = 0; j < 4; ++j)
      Bg[j] = *(const long*)(rb + 4096 + (wn * 8 + 4 + j) * 512 + l * 8);
    STAGE3(H + 3, 2);
    __builtin_amdgcn_s_setprio(1);
    #pragma unroll
    for (int i = 0; i < 4; ++i)
      #pragma unroll
      for (int j = 0; j < 4; ++j)
        acc[i][4 + j] = __builtin_amdgcn_mfma_f32_16x16x32_fp8_fp8(Af[i], Bg[j], acc[i][4 + j], 0, 0, 0);
    __builtin_amdgcn_s_setprio(0);

    // ---- end of n-tile: branchless top-2 fold (+8 bias applied HERE) ----
    if ((H & 15) == 15) {
      int n0 = nStart + ((H >> 4) << 8);
      uint32_t msk[8], nb[8];
      #pragma unroll
      for (int j = 0; j < 8; ++j) {
        int n = n0 + wn * 128 + j * 16 + lrow;
        bool valid = n < nEnd;
        msk[j] = valid ? 0xFFFFF800u : 0u;
        nb[j]  = valid ? (uint32_t)(2047 - (n - nStart)) : 0u;
      }
      #pragma unroll
      for (int i = 0; i < 4; ++i)
        #pragma unroll
        for (int j = 0; j < 8; ++j)
          #pragma unroll
          for (int r = 0; r < 4; ++r) {
            int ss = i * 4 + r;
            uint32_t key = (__builtin_bit_cast(uint32_t, acc[i][j][r] + 8.0f) & msk[j]) | nb[j];
            uint32_t lo = min(K1[ss], key);
            K1[ss] = max(K1[ss], key);
            K2[ss] = max(K2[ss], lo);
          }
    }
  }

  // cross-lane top-2 merge over the 16 lanes sharing each query row
  #pragma unroll
  for (int s = 0; s < 16; ++s) {
    uint32_t k1 = K1[s], k2 = K2[s];
    #pragma unroll
    for (int off = 1; off < 16; off <<= 1) {
      uint32_t o1 = (uint32_t)__shfl_xor((int)k1, off, 64);
      uint32_t o2 = (uint32_t)__shfl_xor((int)k2, off, 64);
      uint32_t nk2 = max(min(k1, o1), max(k2, o2));
      k1 = max(k1, o1);
      k2 = nk2;
    }
    if (lrow == 0) {
      int m = m0 + wm * 64 + (s >> 2) * 16 + (l >> 4) * 4 + (s & 3);
      keys[((size_t)m * NSPLIT + split) * 2 + wn] = make_int2((int)k1, (int)k2);
    }
  }
}

// ---------- fallback (no-ws path): R13 structure, f32 -> bf16 on-the-fly ----------
__global__ __launch_bounds__(256)
__attribute__((amdgpu_waves_per_eu(2, 2)))
void nn_mfma_fb(
    const float* __restrict__ qf, const float* __restrict__ xf,
    const float* __restrict__ rnorm,
    int2* __restrict__ keys, int N) {
  __shared__ __align__(1024) char smem[49152];
  const int tid = threadIdx.x;
  const int l = tid & 63, wv = tid >> 6;
  const int lrow = l & 15;
  const int totTiles = (N + 255) >> 8;
  const int split = blockIdx.x;
  const int m0 = blockIdx.y * BM;
  const int nStart = ((totTiles * split) >> 6) << 8;
  const int nEnd = min(((totTiles * (split + 1)) >> 6) << 8, N);

  uint32_t K1[16], K2[16];
  #pragma unroll
  for (int s = 0; s < 16; ++s) { K1[s] = 0u; K2[s] = 0u; }
  const fvec4 zero4 = {0.f, 0.f, 0.f, 0.f};

  auto STAGE = [&](int c, int sn0, int sk0) {
    char* base = smem + c * 24576;
    #pragma unroll
    for (int u = 0; u < 6; ++u) {
      int unit = tid + 256 * u;
      if (unit < 1024) {
        int row = unit >> 2, kg = unit & 3;
        int boff_l = (row >> 4) * 1024 + kg * 256 + (row & 15) * 16;
        const float* s0 = qf + (size_t)(m0 + row) * DIM + sk0 + kg * 8;
        float4 a0 = *(const float4*)s0, a1 = *(const float4*)(s0 + 4);
        float vv[8] = {a0.x,a0.y,a0.z,a0.w,a1.x,a1.y,a1.z,a1.w};
        ivec4 hw;
        #pragma unroll
        for (int t = 0; t < 4; ++t) {
          ushort_t h0 = bf16_rne(vv[2*t]), h1 = bf16_rne(vv[2*t+1]);
          hw[t] = (int)((uint32_t)h0 | ((uint32_t)h1 << 16));
        }
        *(ivec4*)(base + boff_l) = hw;
      } else {
        int u2 = unit - 1024;
        int row = u2 >> 2, kg = u2 & 3;
        int boff_l = 16384 + (row >> 4) * 1024 + kg * 256 + (row & 15) * 16;
        int gr = min(sn0 + row, N - 1);
        float rn = rnorm[gr];
        const float* s0 = xf + (size_t)gr * DIM + sk0 + kg * 8;
        float4 a0 = *(const float4*)s0, a1 = *(const float4*)(s0 + 4);
        float vv[8] = {a0.x*rn,a0.y*rn,a0.z*rn,a0.w*rn,a1.x*rn,a1.y*rn,a1.z*rn,a1.w*rn};
        ivec4 hw;
        #pragma unroll
        for (int t = 0; t < 4; ++t) {
          ushort_t h0 = bf16_rne(vv[2*t]), h1 = bf16_rne(vv[2*t+1]);
          hw[t] = (int)((uint32_t)h0 | ((uint32_t)h1 << 16));
        }
        *(ivec4*)(base + boff_l) = hw;
      }
    }
  };

  const int nTiles = (nEnd - nStart + 127) >> 7;
  const int S = nTiles * 16;
  STAGE(0, nStart, 0);
  if (S > 1) STAGE(1 % 3, nStart, 32);
  __syncthreads();

  fvec4 acc[4][8];
  #pragma unroll 1
  for (int s = 0; s < S; ++s) {
    if ((s & 15) == 0) {
      #pragma unroll
      for (int i = 0; i < 4; ++i)
        #pragma unroll
        for (int j = 0; j < 8; ++j) acc[i][j] = zero4;
    }
    if (s + 2 < S) STAGE((s + 2) % 3, nStart + (((s + 2) >> 4) * 128), ((s + 2) & 15) * 32);
    const char* rb = smem + (s % 3) * 24576;
    bvec8 Ah[4], Bh[8];
    #pragma unroll
    for (int i = 0; i < 4; ++i)
      Ah[i] = __builtin_bit_cast(bvec8, *(const ivec4*)(rb + (wv*4 + i) * 1024 + l * 16));
    #pragma unroll
    for (int j = 0; j < 8; ++j)
      Bh[j] = __builtin_bit_cast(bvec8, *(const ivec4*)(rb + 16384 + j * 1024 + l * 16));
    #pragma unroll
    for (int i = 0; i < 4; ++i)
      #pragma unroll
      for (int j = 0; j < 8; ++j)
        acc[i][j] = __builtin_amdgcn_mfma_f32_16x16x32_bf16(Ah[i], Bh[j], acc[i][j], 0, 0, 0);
    if ((s & 15) == 15) {
      int n0 = nStart + ((s >> 4) * 128);
      uint32_t msk[8], nb[8];
      #pragma unroll
      for (int j = 0; j < 8; ++j) {
        int n = n0 + j * 16 + lrow;
        bool valid = n < nEnd;
        msk[j] = valid ? 0xFFFFF800u : 0u;
        nb[j]  = valid ? (uint32_t)(2047 - (n - nStart)) : 0u;
      }
      #pragma unroll
      for (int i = 0; i < 4; ++i)
        #pragma unroll
        for (int j = 0; j < 8; ++j)
          #pragma unroll
          for (int r = 0; r < 4; ++r) {
            int ss = i * 4 + r;
            uint32_t key = (__builtin_bit_cast(uint32_t, acc[i][j][r] + 8.0f) & msk[j]) | nb[j];
            uint32_t lo = min(K1[ss], key);
            K1[ss] = max(K1[ss], key);
            K2[ss] = max(K2[ss], lo);
          }
    }
    __syncthreads();
  }

  #pragma unroll
  for (int s = 0; s < 16; ++s) {
    uint32_t k1 = K1[s], k2 = K2[s];
    #pragma unroll
    for (int off = 1; off < 16; off <<= 1) {
      uint32_t o1 = (uint32_t)__shfl_xor((int)k1, off, 64);
      uint32_t o2 = (uint32_t)__shfl_xor((int)k2, off, 64);
      uint32_t nk2 = max(min(k1, o1), max(k2, o2));
      k1 = max(k1, o1);
      k2 = nk2;
    }
    if (lrow == 0) {
      int m = m0 + wv * 64 + (s >> 2) * 16 + (l >> 4) * 4 + (s & 3);
      keys[((size_t)m * NSPLIT + split) * 2 + 0] = make_int2((int)k1, (int)k2);
      keys[((size_t)m * NSPLIT + split) * 2 + 1] = make_int2(0, 0);
    }
  }
}

// ---------- finalize: unpack 256 candidate slots, exact f32 rescore, one-hot ----------
__global__ __launch_bounds__(256) void finalize_kernel(
    const int2* __restrict__ keys,
    const float* __restrict__ qf, const float* __restrict__ xf,
    const float* __restrict__ rnorm, const int* __restrict__ y,
    int* __restrict__ out, int N) {
  int m = blockIdx.x;
  int tid = threadIdx.x, l = tid & 63, w = tid >> 6;
  const int totTiles = (N + 255) >> 8;
  __shared__ float sv[256]; __shared__ int si[256];
  __shared__ float swm[4];
  __shared__ float swv[4]; __shared__ int swi[4];
  __shared__ int s_label;
  {
    int slot = tid >> 1;                       // split*2 + wn
    int2 kk = keys[(size_t)m * 128 + slot];
    uint32_t k = (tid & 1) ? (uint32_t)kk.y : (uint32_t)kk.x;
    float v; int idx;
    if (k == 0) { v = -FLT_MAX; idx = 0x7fffffff; }
    else {
      int sp = slot >> 1;
      int nStart = ((totTiles * sp) >> 6) << 8;
      v = __builtin_bit_cast(float, k & 0xFFFFF800u) - 8.0f;
      idx = nStart + 2047 - (int)(k & 0x7FFu);
    }
    sv[tid] = v; si[tid] = idx;
  }
  __syncthreads();
  float v = sv[tid];
  #pragma unroll
  for (int off = 1; off < 64; off <<= 1) v = fmaxf(v, __shfl_xor(v, off, 64));
  if (l == 0) swm[w] = v;
  __syncthreads();
  float svmax = fmaxf(fmaxf(swm[0], swm[1]), fmaxf(swm[2], swm[3]));
  float thresh = svmax - MARGIN;
  float bestv = -FLT_MAX; int besti = 0x7fffffff;
  for (int cc = 0; cc < 64; ++cc) {
    int c = w * 64 + cc;
    float av = sv[c]; int idx = si[c];
    if (av < thresh) continue;  // wave-uniform branch
    const float4* qp = (const float4*)(qf + (size_t)m * DIM);
    const float4* xp = (const float4*)(xf + (size_t)idx * DIM);
    float s = 0.f;
    #pragma unroll
    for (int t = 0; t < 2; ++t) {
      float4 qa = qp[l * 2 + t], xa = xp[l * 2 + t];
      s += qa.x*xa.x + qa.y*xa.y + qa.z*xa.z + qa.w*xa.w;
    }
    #pragma unroll
    for (int off = 1; off < 64; off <<= 1) s += __shfl_xor(s, off, 64);
    float ev = s * rnorm[idx];
    if (ev > bestv || (ev == bestv && idx < besti)) { bestv = ev; besti = idx; }
  }
  if (l == 0) { swv[w] = bestv; swi[w] = besti; }
  __syncthreads();
  if (tid == 0) {
    float bv = swv[0]; int bi = swi[0];
    #pragma unroll
    for (int k = 1; k < 4; ++k)
      if (swv[k] > bv || (swv[k] == bv && swi[k] < bi)) { bv = swv[k]; bi = swi[k]; }
    s_label = y[bi];
  }
  __syncthreads();
  int label = s_label;
  for (int c = tid; c < NUM_CLASSES; c += 256)
    out[(size_t)m * NUM_CLASSES + c] = (c == label) ? 1 : 0;
}

extern "C" void kernel_launch(void* const* d_in, const int* in_sizes, int n_in,
                              void* d_out, int out_size, void* d_ws, size_t ws_size,
                              hipStream_t stream) {
  const float* x = (const float*)d_in[0];   // [N, 512]
  const int*   y = (const int*)d_in[1];     // [N]
  const float* q = (const float*)d_in[2];   // [M, 512]
  int N = in_sizes[0] / DIM;                // 100000
  int M = in_sizes[2] / DIM;                // 2048
  int* out = (int*)d_out;
  int totTiles = (N + 255) >> 8;            // 391
  int padN = totTiles << 8;                 // 100096

  // workspace layout (fp8 blob arrays: ~52MB total)
  size_t off = 0;
  float* rnorm = (float*)((char*)d_ws + off); off += (((size_t)N * 4 + 1023) / 1024) * 1024;
  int2* keys   = (int2*)((char*)d_ws + off);  off += (size_t)M * NSPLIT * 2 * 8;
  unsigned char* qb8 = (unsigned char*)d_ws + off; off += (size_t)M * DIM;
  unsigned char* xb8 = (unsigned char*)d_ws + off; off += (size_t)padN * DIM;
  bool pre = (ws_size >= off);

  if (pre) {
    prep_fp8<<<(padN * 16 + 255) / 256, 256, 0, stream>>>(x, rnorm, xb8, N, padN, 1);
    prep_fp8<<<(M * 16 + 255) / 256, 256, 0, stream>>>(q, nullptr, qb8, M, M, 0);
    dim3 grid(NSPLIT, M / 128);               // 64 x 16 = 1024 blocks, 2/CU resident
    nn_mfma8<<<grid, 256, 0, stream>>>(qb8, xb8, keys, N);
  } else {
    prep_fp8<<<(N * 16 + 255) / 256, 256, 0, stream>>>(x, rnorm, nullptr, N, N, 1);
    dim3 gridf(NSPLIT, M / BM);               // fallback: bf16 on-the-fly
    nn_mfma_fb<<<gridf, 256, 0, stream>>>(q, x, rnorm, keys, N);
  }
  finalize_kernel<<<M, 256, 0, stream>>>(keys, q, x, rnorm, y, out, N);
}

// Round 21
// 233.976 us; speedup vs baseline: 1.4276x; 1.0356x over previous
//
#include <hip/hip_runtime.h>
#include <float.h>
#include <stdint.h>

#define DIM 512
#define BM 256   // fallback geometry only; main kernel uses 128x256 literals
#define NSPLIT 64
#define NUM_CLASSES 1000
#define MARGIN 0.5f   // fp8 screen: dot sigma ~0.05-0.08 -> ~6-sigma rescore margin

typedef unsigned short ushort_t;
typedef __attribute__((ext_vector_type(4))) float fvec4;
typedef __attribute__((ext_vector_type(8))) __bf16 bvec8;
typedef __attribute__((ext_vector_type(4))) int ivec4;

#define AS1 __attribute__((address_space(1)))
#define AS3 __attribute__((address_space(3)))

__device__ inline ushort_t bf16_rne(float f) {
  uint32_t u = __builtin_bit_cast(uint32_t, f);
  uint32_t r = u + 0x7fffu + ((u >> 16) & 1u);
  return (ushort_t)(r >> 16);
}

// ---------- prep: rnorm + f32 -> fp8 e4m3 BLOB-format array ----------
// Blob = 16 rows x 32 k of fp8 (512B), interior byte(r,k) = (k>>3)*128 + r*8 + (k&7)
// Array layout: [row>>8][kchunk 0..15][rowgrp 0..15][512B]
__global__ __launch_bounds__(256) void prep_fp8(
    const float* __restrict__ src, float* __restrict__ rnorm_out,
    unsigned char* __restrict__ dst, int rows, int padRows, int scale) {
  int idx = blockIdx.x * 256 + threadIdx.x;
  if (idx >= padRows * 16) return;
  int row = idx >> 4, kc = idx & 15;
  int srow = min(row, rows - 1);             // pad rows replicate last row
  const float* s0 = src + (size_t)srow * DIM + kc * 32;
  float v[32];
  #pragma unroll
  for (int t = 0; t < 8; ++t) {
    float4 a = *(const float4*)(s0 + t * 4);
    v[4*t] = a.x; v[4*t+1] = a.y; v[4*t+2] = a.z; v[4*t+3] = a.w;
  }
  float rn = 1.0f;
  if (scale) {
    float s = 0.f;
    #pragma unroll
    for (int t = 0; t < 32; ++t) s += v[t] * v[t];
    #pragma unroll
    for (int off = 1; off < 16; off <<= 1) s += __shfl_xor(s, off, 64);
    rn = 1.0f / fmaxf(sqrtf(s), 1e-12f);
    if (rnorm_out && kc == 0 && row < rows) rnorm_out[row] = rn;
  }
  unsigned char* blob = dst + (((size_t)(row >> 8) * 16 + kc) * 16 + ((row >> 4) & 15)) * 512;
  int rr = row & 15;
  #pragma unroll
  for (int g = 0; g < 4; ++g) {
    int w0 = 0, w1 = 0;
    w0 = __builtin_amdgcn_cvt_pk_fp8_f32(v[8*g+0]*rn, v[8*g+1]*rn, w0, false);
    w0 = __builtin_amdgcn_cvt_pk_fp8_f32(v[8*g+2]*rn, v[8*g+3]*rn, w0, true);
    w1 = __builtin_amdgcn_cvt_pk_fp8_f32(v[8*g+4]*rn, v[8*g+5]*rn, w1, false);
    w1 = __builtin_amdgcn_cvt_pk_fp8_f32(v[8*g+6]*rn, v[8*g+7]*rn, w1, true);
    *(int2*)(blob + g * 128 + rr * 8) = make_int2(w0, w1);
  }
}

// ---------- screen (main): 4-wave 128x256 blocks, fp8 MFMA, K=64 halves ----------
// R20 (198us, MfmaUtil 45): barrier per 16 MFMA + per-half VALU bookkeeping is the
// remaining overhead (VALUBusy 37%). R21: half = K=64. Buffer 24KB (A 8K | B 16K),
// 3 buffers = 72KB/block -> still 2 blocks/CU (144 <= 160). Per half: 6 x 1KB
// stage loads/wave (counted vmcnt(6), 1 half in flight, clamp-idempotent tail --
// skipping tail stages would break the vmcnt accounting), 2 phases of
// {12 b64 reads, 32 MFMA} -> barriers per MFMA halved, bookkeeping halved.
// Banked: bias at FOLD only; split=(bx+8*by)&63 (XCD locality); tile-exact splits.
__global__ __launch_bounds__(256)
__attribute__((amdgpu_waves_per_eu(2, 2)))
void nn_mfma8(
    const unsigned char* __restrict__ qb, const unsigned char* __restrict__ xb,
    int2* __restrict__ keys, int N) {
  __shared__ __align__(1024) char smem[73728];    // 3 buffers x 24KB
  const int tid = threadIdx.x;
  const int l = tid & 63, w = tid >> 6;           // 4 waves
  const int wm = w >> 1, wn = w & 1;              // 2M x 2N; wave tile 64 x 128
  const int lrow = l & 15;
  const int totTiles = (N + 255) >> 8;            // 391
  const int split = (blockIdx.x + 8 * blockIdx.y) & (NSPLIT - 1);
  const int mb = blockIdx.y;                      // 16 m-blocks of 128 rows
  const int m0 = mb * 128;
  const int T0 = (totTiles * split) >> 6;
  const int T1 = (totTiles * (split + 1)) >> 6;
  const int nStart = T0 << 8;
  const int nEnd = min(T1 << 8, N);
  const int nTiles = T1 - T0;
  const int nH = nTiles * 8;                      // 8 K=64 halves per 256-wide tile

  uint32_t K1[16], K2[16];
  #pragma unroll
  for (int s = 0; s < 16; ++s) { K1[s] = 0u; K2[s] = 0u; }

  // A blob (kc, g) source: ((mb>>1)*16 + kc)*16 + (mb&1)*8 + g)*512
  const unsigned char* srcA0 = qb + (((size_t)(mb >> 1) * 256) + (mb & 1) * 8) * 512;

  // stage part p of half Hs (each call = 2x 1KB loads, except p0 = 2 loads too):
  //  p0: A kc2={0,1}, rowgrps {2w,2w+1}   (2 loads)
  //  p1: B kc2=0, rowgrps {4w..4w+3}      (2 loads)
  //  p2: B kc2=1, rowgrps {4w..4w+3}      (2 loads)
  auto STAGE = [&](int Hs, int p) {
    Hs = min(Hs, nH - 1);
    char* base = smem + (Hs % 3) * 24576;
    int kcb = (Hs & 7) * 2;                       // first kc of the half
    if (p == 0) {
      #pragma unroll
      for (int kc2 = 0; kc2 < 2; ++kc2) {
        const unsigned char* src = srcA0 + ((size_t)(kcb + kc2) * 16 + 2 * w) * 512;
        __builtin_amdgcn_global_load_lds((const AS1 int*)(src + l * 16),
                                         (AS3 int*)(base + kc2 * 4096 + w * 1024), 16, 0, 0);
      }
    } else {
      int kc2 = p - 1;
      int T = T0 + (Hs >> 3);
      #pragma unroll
      for (int t = 0; t < 2; ++t) {
        int g0 = 4 * w + 2 * t;
        const unsigned char* src = xb + (((size_t)T * 16 + kcb + kc2) * 16 + g0) * 512;
        __builtin_amdgcn_global_load_lds((const AS1 int*)(src + l * 16),
                                         (AS3 int*)(base + 8192 + kc2 * 8192 + g0 * 512), 16, 0, 0);
      }
    }
  };

  // prologue: 2 halves in flight (6 loads/wave/half)
  STAGE(0, 0); STAGE(0, 1); STAGE(0, 2);
  STAGE(1, 0); STAGE(1, 1); STAGE(1, 2);

  fvec4 acc[4][8];
  const fvec4 zero4 = {0.f, 0.f, 0.f, 0.f};       // bias at fold, NOT here

  #pragma unroll 1
  for (int H = 0; H < nH; ++H) {
    if ((H & 7) == 0) {
      #pragma unroll
      for (int i = 0; i < 4; ++i)
        #pragma unroll
        for (int j = 0; j < 8; ++j) acc[i][j] = zero4;
    }
    const char* rb = smem + (H % 3) * 24576;

    // ---- phase 0 (kc2=0): counted-vmcnt barrier, A(4)+B(8) b64, stage p0+p1, 32 MFMA ----
    asm volatile("s_waitcnt vmcnt(6)\n\ts_barrier" ::: "memory");
    __builtin_amdgcn_sched_barrier(0);
    long Af[4], Bf[8];
    #pragma unroll
    for (int i = 0; i < 4; ++i)
      Af[i] = *(const long*)(rb + (wm * 4 + i) * 512 + l * 8);
    #pragma unroll
    for (int j = 0; j < 8; ++j)
      Bf[j] = *(const long*)(rb + 8192 + (wn * 8 + j) * 512 + l * 8);
    STAGE(H + 2, 0);
    STAGE(H + 2, 1);
    __builtin_amdgcn_s_setprio(1);
    #pragma unroll
    for (int i = 0; i < 4; ++i)
      #pragma unroll
      for (int j = 0; j < 8; ++j)
        acc[i][j] = __builtin_amdgcn_mfma_f32_16x16x32_fp8_fp8(Af[i], Bf[j], acc[i][j], 0, 0, 0);
    __builtin_amdgcn_s_setprio(0);

    // ---- phase 1 (kc2=1): barrier, A(4)+B(8) b64, stage p2, 32 MFMA ----
    __builtin_amdgcn_s_barrier();
    long Ag[4], Bg[8];
    #pragma unroll
    for (int i = 0; i < 4; ++i)
      Ag[i] = *(const long*)(rb + 4096 + (wm * 4 + i) * 512 + l * 8);
    #pragma unroll
    for (int j = 0; j < 8; ++j)
      Bg[j] = *(const long*)(rb + 16384 + (wn * 8 + j) * 512 + l * 8);
    STAGE(H + 2, 2);
    __builtin_amdgcn_s_setprio(1);
    #pragma unroll
    for (int i = 0; i < 4; ++i)
      #pragma unroll
      for (int j = 0; j < 8; ++j)
        acc[i][j] = __builtin_amdgcn_mfma_f32_16x16x32_fp8_fp8(Ag[i], Bg[j], acc[i][j], 0, 0, 0);
    __builtin_amdgcn_s_setprio(0);

    // ---- end of n-tile: branchless top-2 fold (+8 bias applied HERE) ----
    if ((H & 7) == 7) {
      int n0 = nStart + ((H >> 3) << 8);
      uint32_t msk[8], nb[8];
      #pragma unroll
      for (int j = 0; j < 8; ++j) {
        int n = n0 + wn * 128 + j * 16 + lrow;
        bool valid = n < nEnd;
        msk[j] = valid ? 0xFFFFF800u : 0u;
        nb[j]  = valid ? (uint32_t)(2047 - (n - nStart)) : 0u;
      }
      #pragma unroll
      for (int i = 0; i < 4; ++i)
        #pragma unroll
        for (int j = 0; j < 8; ++j)
          #pragma unroll
          for (int r = 0; r < 4; ++r) {
            int ss = i * 4 + r;
            uint32_t key = (__builtin_bit_cast(uint32_t, acc[i][j][r] + 8.0f) & msk[j]) | nb[j];
            uint32_t lo = min(K1[ss], key);
            K1[ss] = max(K1[ss], key);
            K2[ss] = max(K2[ss], lo);
          }
    }
  }

  // cross-lane top-2 merge over the 16 lanes sharing each query row
  #pragma unroll
  for (int s = 0; s < 16; ++s) {
    uint32_t k1 = K1[s], k2 = K2[s];
    #pragma unroll
    for (int off = 1; off < 16; off <<= 1) {
      uint32_t o1 = (uint32_t)__shfl_xor((int)k1, off, 64);
      uint32_t o2 = (uint32_t)__shfl_xor((int)k2, off, 64);
      uint32_t nk2 = max(min(k1, o1), max(k2, o2));
      k1 = max(k1, o1);
      k2 = nk2;
    }
    if (lrow == 0) {
      int m = m0 + wm * 64 + (s >> 2) * 16 + (l >> 4) * 4 + (s & 3);
      keys[((size_t)m * NSPLIT + split) * 2 + wn] = make_int2((int)k1, (int)k2);
    }
  }
}

// ---------- fallback (no-ws path): R13 structure, f32 -> bf16 on-the-fly ----------
__global__ __launch_bounds__(256)
__attribute__((amdgpu_waves_per_eu(2, 2)))
void nn_mfma_fb(
    const float* __restrict__ qf, const float* __restrict__ xf,
    const float* __restrict__ rnorm,
    int2* __restrict__ keys, int N) {
  __shared__ __align__(1024) char smem[49152];
  const int tid = threadIdx.x;
  const int l = tid & 63, wv = tid >> 6;
  const int lrow = l & 15;
  const int totTiles = (N + 255) >> 8;
  const int split = blockIdx.x;
  const int m0 = blockIdx.y * BM;
  const int nStart = ((totTiles * split) >> 6) << 8;
  const int nEnd = min(((totTiles * (split + 1)) >> 6) << 8, N);

  uint32_t K1[16], K2[16];
  #pragma unroll
  for (int s = 0; s < 16; ++s) { K1[s] = 0u; K2[s] = 0u; }
  const fvec4 zero4 = {0.f, 0.f, 0.f, 0.f};

  auto STAGE = [&](int c, int sn0, int sk0) {
    char* base = smem + c * 24576;
    #pragma unroll
    for (int u = 0; u < 6; ++u) {
      int unit = tid + 256 * u;
      if (unit < 1024) {
        int row = unit >> 2, kg = unit & 3;
        int boff_l = (row >> 4) * 1024 + kg * 256 + (row & 15) * 16;
        const float* s0 = qf + (size_t)(m0 + row) * DIM + sk0 + kg * 8;
        float4 a0 = *(const float4*)s0, a1 = *(const float4*)(s0 + 4);
        float vv[8] = {a0.x,a0.y,a0.z,a0.w,a1.x,a1.y,a1.z,a1.w};
        ivec4 hw;
        #pragma unroll
        for (int t = 0; t < 4; ++t) {
          ushort_t h0 = bf16_rne(vv[2*t]), h1 = bf16_rne(vv[2*t+1]);
          hw[t] = (int)((uint32_t)h0 | ((uint32_t)h1 << 16));
        }
        *(ivec4*)(base + boff_l) = hw;
      } else {
        int u2 = unit - 1024;
        int row = u2 >> 2, kg = u2 & 3;
        int boff_l = 16384 + (row >> 4) * 1024 + kg * 256 + (row & 15) * 16;
        int gr = min(sn0 + row, N - 1);
        float rn = rnorm[gr];
        const float* s0 = xf + (size_t)gr * DIM + sk0 + kg * 8;
        float4 a0 = *(const float4*)s0, a1 = *(const float4*)(s0 + 4);
        float vv[8] = {a0.x*rn,a0.y*rn,a0.z*rn,a0.w*rn,a1.x*rn,a1.y*rn,a1.z*rn,a1.w*rn};
        ivec4 hw;
        #pragma unroll
        for (int t = 0; t < 4; ++t) {
          ushort_t h0 = bf16_rne(vv[2*t]), h1 = bf16_rne(vv[2*t+1]);
          hw[t] = (int)((uint32_t)h0 | ((uint32_t)h1 << 16));
        }
        *(ivec4*)(base + boff_l) = hw;
      }
    }
  };

  const int nTiles = (nEnd - nStart + 127) >> 7;
  const int S = nTiles * 16;
  STAGE(0, nStart, 0);
  if (S > 1) STAGE(1 % 3, nStart, 32);
  __syncthreads();

  fvec4 acc[4][8];
  #pragma unroll 1
  for (int s = 0; s < S; ++s) {
    if ((s & 15) == 0) {
      #pragma unroll
      for (int i = 0; i < 4; ++i)
        #pragma unroll
        for (int j = 0; j < 8; ++j) acc[i][j] = zero4;
    }
    if (s + 2 < S) STAGE((s + 2) % 3, nStart + (((s + 2) >> 4) * 128), ((s + 2) & 15) * 32);
    const char* rb = smem + (s % 3) * 24576;
    bvec8 Ah[4], Bh[8];
    #pragma unroll
    for (int i = 0; i < 4; ++i)
      Ah[i] = __builtin_bit_cast(bvec8, *(const ivec4*)(rb + (wv*4 + i) * 1024 + l * 16));
    #pragma unroll
    for (int j = 0; j < 8; ++j)
      Bh[j] = __builtin_bit_cast(bvec8, *(const ivec4*)(rb + 16384 + j * 1024 + l * 16));
    #pragma unroll
    for (int i = 0; i < 4; ++i)
      #pragma unroll
      for (int j = 0; j < 8; ++j)
        acc[i][j] = __builtin_amdgcn_mfma_f32_16x16x32_bf16(Ah[i], Bh[j], acc[i][j], 0, 0, 0);
    if ((s & 15) == 15) {
      int n0 = nStart + ((s >> 4) * 128);
      uint32_t msk[8], nb[8];
      #pragma unroll
      for (int j = 0; j < 8; ++j) {
        int n = n0 + j * 16 + lrow;
        bool valid = n < nEnd;
        msk[j] = valid ? 0xFFFFF800u : 0u;
        nb[j]  = valid ? (uint32_t)(2047 - (n - nStart)) : 0u;
      }
      #pragma unroll
      for (int i = 0; i < 4; ++i)
        #pragma unroll
        for (int j = 0; j < 8; ++j)
          #pragma unroll
          for (int r = 0; r < 4; ++r) {
            int ss = i * 4 + r;
            uint32_t key = (__builtin_bit_cast(uint32_t, acc[i][j][r] + 8.0f) & msk[j]) | nb[j];
            uint32_t lo = min(K1[ss], key);
            K1[ss] = max(K1[ss], key);
            K2[ss] = max(K2[ss], lo);
          }
    }
    __syncthreads();
  }

  #pragma unroll
  for (int s = 0; s < 16; ++s) {
    uint32_t k1 = K1[s], k2 = K2[s];
    #pragma unroll
    for (int off = 1; off < 16; off <<= 1) {
      uint32_t o1 = (uint32_t)__shfl_xor((int)k1, off, 64);
      uint32_t o2 = (uint32_t)__shfl_xor((int)k2, off, 64);
      uint32_t nk2 = max(min(k1, o1), max(k2, o2));
      k1 = max(k1, o1);
      k2 = nk2;
    }
    if (lrow == 0) {
      int m = m0 + wv * 64 + (s >> 2) * 16 + (l >> 4) * 4 + (s & 3);
      keys[((size_t)m * NSPLIT + split) * 2 + 0] = make_int2((int)k1, (int)k2);
      keys[((size_t)m * NSPLIT + split) * 2 + 1] = make_int2(0, 0);
    }
  }
}

// ---------- finalize: unpack 256 candidate slots, exact f32 rescore, one-hot ----------
__global__ __launch_bounds__(256) void finalize_kernel(
    const int2* __restrict__ keys,
    const float* __restrict__ qf, const float* __restrict__ xf,
    const float* __restrict__ rnorm, const int* __restrict__ y,
    int* __restrict__ out, int N) {
  int m = blockIdx.x;
  int tid = threadIdx.x, l = tid & 63, w = tid >> 6;
  const int totTiles = (N + 255) >> 8;
  __shared__ float sv[256]; __shared__ int si[256];
  __shared__ float swm[4];
  __shared__ float swv[4]; __shared__ int swi[4];
  __shared__ int s_label;
  {
    int slot = tid >> 1;                       // split*2 + wn
    int2 kk = keys[(size_t)m * 128 + slot];
    uint32_t k = (tid & 1) ? (uint32_t)kk.y : (uint32_t)kk.x;
    float v; int idx;
    if (k == 0) { v = -FLT_MAX; idx = 0x7fffffff; }
    else {
      int sp = slot >> 1;
      int nStart = ((totTiles * sp) >> 6) << 8;
      v = __builtin_bit_cast(float, k & 0xFFFFF800u) - 8.0f;
      idx = nStart + 2047 - (int)(k & 0x7FFu);
    }
    sv[tid] = v; si[tid] = idx;
  }
  __syncthreads();
  float v = sv[tid];
  #pragma unroll
  for (int off = 1; off < 64; off <<= 1) v = fmaxf(v, __shfl_xor(v, off, 64));
  if (l == 0) swm[w] = v;
  __syncthreads();
  float svmax = fmaxf(fmaxf(swm[0], swm[1]), fmaxf(swm[2], swm[3]));
  float thresh = svmax - MARGIN;
  float bestv = -FLT_MAX; int besti = 0x7fffffff;
  for (int cc = 0; cc < 64; ++cc) {
    int c = w * 64 + cc;
    float av = sv[c]; int idx = si[c];
    if (av < thresh) continue;  // wave-uniform branch
    const float4* qp = (const float4*)(qf + (size_t)m * DIM);
    const float4* xp = (const float4*)(xf + (size_t)idx * DIM);
    float s = 0.f;
    #pragma unroll
    for (int t = 0; t < 2; ++t) {
      float4 qa = qp[l * 2 + t], xa = xp[l * 2 + t];
      s += qa.x*xa.x + qa.y*xa.y + qa.z*xa.z + qa.w*xa.w;
    }
    #pragma unroll
    for (int off = 1; off < 64; off <<= 1) s += __shfl_xor(s, off, 64);
    float ev = s * rnorm[idx];
    if (ev > bestv || (ev == bestv && idx < besti)) { bestv = ev; besti = idx; }
  }
  if (l == 0) { swv[w] = bestv; swi[w] = besti; }
  __syncthreads();
  if (tid == 0) {
    float bv = swv[0]; int bi = swi[0];
    #pragma unroll
    for (int k = 1; k < 4; ++k)
      if (swv[k] > bv || (swv[k] == bv && swi[k] < bi)) { bv = swv[k]; bi = swi[k]; }
    s_label = y[bi];
  }
  __syncthreads();
  int label = s_label;
  for (int c = tid; c < NUM_CLASSES; c += 256)
    out[(size_t)m * NUM_CLASSES + c] = (c == label) ? 1 : 0;
}

extern "C" void kernel_launch(void* const* d_in, const int* in_sizes, int n_in,
                              void* d_out, int out_size, void* d_ws, size_t ws_size,
                              hipStream_t stream) {
  const float* x = (const float*)d_in[0];   // [N, 512]
  const int*   y = (const int*)d_in[1];     // [N]
  const float* q = (const float*)d_in[2];   // [M, 512]
  int N = in_sizes[0] / DIM;                // 100000
  int M = in_sizes[2] / DIM;                // 2048
  int* out = (int*)d_out;
  int totTiles = (N + 255) >> 8;            // 391
  int padN = totTiles << 8;                 // 100096

  // workspace layout (fp8 blob arrays: ~52MB total)
  size_t off = 0;
  float* rnorm = (float*)((char*)d_ws + off); off += (((size_t)N * 4 + 1023) / 1024) * 1024;
  int2* keys   = (int2*)((char*)d_ws + off);  off += (size_t)M * NSPLIT * 2 * 8;
  unsigned char* qb8 = (unsigned char*)d_ws + off; off += (size_t)M * DIM;
  unsigned char* xb8 = (unsigned char*)d_ws + off; off += (size_t)padN * DIM;
  bool pre = (ws_size >= off);

  if (pre) {
    prep_fp8<<<(padN * 16 + 255) / 256, 256, 0, stream>>>(x, rnorm, xb8, N, padN, 1);
    prep_fp8<<<(M * 16 + 255) / 256, 256, 0, stream>>>(q, nullptr, qb8, M, M, 0);
    dim3 grid(NSPLIT, M / 128);               // 64 x 16 = 1024 blocks, 2/CU resident
    nn_mfma8<<<grid, 256, 0, stream>>>(qb8, xb8, keys, N);
  } else {
    prep_fp8<<<(N * 16 + 255) / 256, 256, 0, stream>>>(x, rnorm, nullptr, N, N, 1);
    dim3 gridf(NSPLIT, M / BM);               // fallback: bf16 on-the-fly
    nn_mfma_fb<<<gridf, 256, 0, stream>>>(q, x, rnorm, keys, N);
  }
  finalize_kernel<<<M, 256, 0, stream>>>(keys, q, x, rnorm, y, out, N);
}

// Round 22
// 190.365 us; speedup vs baseline: 1.7547x; 1.2291x over previous
//
#include <hip/hip_runtime.h>
#include <float.h>
#include <stdint.h>

#define DIM 512
#define BM 256   // fallback geometry only; main kernel uses 128x128 literals
#define NSPLIT 64
#define NUM_CLASSES 1000
#define MARGIN 0.5f   // fp8 screen: dot sigma ~0.05-0.08 -> ~6-sigma rescore margin

typedef unsigned short ushort_t;
typedef __attribute__((ext_vector_type(4))) float fvec4;
typedef __attribute__((ext_vector_type(8))) __bf16 bvec8;
typedef __attribute__((ext_vector_type(4))) int ivec4;
typedef __attribute__((ext_vector_type(8))) int ivec8;

#define AS1 __attribute__((address_space(1)))
#define AS3 __attribute__((address_space(3)))

__device__ inline ushort_t bf16_rne(float f) {
  uint32_t u = __builtin_bit_cast(uint32_t, f);
  uint32_t r = u + 0x7fffu + ((u >> 16) & 1u);
  return (ushort_t)(r >> 16);
}

// ---------- prep: rnorm + f32 -> fp8 e4m3 K128-BLOB array ----------
// Blob = 16 rows x 128 k of fp8 (2KB). Interior = lane-linear16 pairs:
//   lane l <-> (r=l&15, kc=l>>4); its k-window = kc*32..+32.
//   lo 16B (k 0..15 of window) at blob + l*16; hi 16B at blob + 1024 + l*16.
// Array: [row>>8][kc128 0..3][rowgrp 0..15][2048B]. Thread = (row, kc32).
__global__ __launch_bounds__(256) void prep_fp8(
    const float* __restrict__ src, float* __restrict__ rnorm_out,
    unsigned char* __restrict__ dst, int rows, int padRows, int scale) {
  int idx = blockIdx.x * 256 + threadIdx.x;
  if (idx >= padRows * 16) return;
  int row = idx >> 4, kc = idx & 15;
  int srow = min(row, rows - 1);             // pad rows replicate last row
  const float* s0 = src + (size_t)srow * DIM + kc * 32;
  float v[32];
  #pragma unroll
  for (int t = 0; t < 8; ++t) {
    float4 a = *(const float4*)(s0 + t * 4);
    v[4*t] = a.x; v[4*t+1] = a.y; v[4*t+2] = a.z; v[4*t+3] = a.w;
  }
  float rn = 1.0f;
  if (scale) {
    float s = 0.f;
    #pragma unroll
    for (int t = 0; t < 32; ++t) s += v[t] * v[t];
    #pragma unroll
    for (int off = 1; off < 16; off <<= 1) s += __shfl_xor(s, off, 64);
    rn = 1.0f / fmaxf(sqrtf(s), 1e-12f);
    if (rnorm_out && kc == 0 && row < rows) rnorm_out[row] = rn;
  }
  unsigned char* blob = dst + (((size_t)(row >> 8) * 4 + (kc >> 2)) * 16 + ((row >> 4) & 15)) * 2048;
  int lo_off = ((kc & 3) * 16 + (row & 15)) * 16;
  ivec4 lo4, hi4;
  #pragma unroll
  for (int t = 0; t < 4; ++t) {
    int wl = 0, wh = 0;
    wl = __builtin_amdgcn_cvt_pk_fp8_f32(v[4*t+0]*rn, v[4*t+1]*rn, wl, false);
    wl = __builtin_amdgcn_cvt_pk_fp8_f32(v[4*t+2]*rn, v[4*t+3]*rn, wl, true);
    wh = __builtin_amdgcn_cvt_pk_fp8_f32(v[16+4*t+0]*rn, v[16+4*t+1]*rn, wh, false);
    wh = __builtin_amdgcn_cvt_pk_fp8_f32(v[16+4*t+2]*rn, v[16+4*t+3]*rn, wh, true);
    lo4[t] = wl; hi4[t] = wh;
  }
  *(ivec4*)(blob + lo_off) = lo4;
  *(ivec4*)(blob + 1024 + lo_off) = hi4;
}

// ---------- screen (main): MX-scaled fp8 K=128, 4-wave 128x128 blocks ----------
// R21 ceiling: non-scaled fp8 MFMA floor 101us, we sat at 189 (53%). MX K=128
// (mfma_scale_f32_16x16x128_f8f6f4, unit E8M0 scales = 127) halves matrix-pipe
// cycles for the same bytes. Wave tile 64x64 (acc 64 VGPR), double-buffered
// 32KB buffers -> 64KB/block -> 2 blocks/CU (R20's cross-block overlap covers
// the vmcnt(0) drain; no tail stages -> no counted-vmcnt bookkeeping needed).
// Fragment reads keep the proven l*16 b128 pattern (2 halves per 32B operand);
// any within-lane k-permutation vs HW cancels (A/B layouts identical).
// Banked: bias at FOLD only; split=(bx+8*by)&63; tile-exact splits.
__global__ __launch_bounds__(256)
__attribute__((amdgpu_waves_per_eu(2, 2)))
void nn_mx(
    const unsigned char* __restrict__ qb, const unsigned char* __restrict__ xb,
    int2* __restrict__ keys, int N) {
  __shared__ __align__(1024) char smem[65536];    // 2 buffers x (A 16KB | B 16KB)
  const int tid = threadIdx.x;
  const int l = tid & 63, w = tid >> 6;           // 4 waves
  const int wm = w >> 1, wn = w & 1;              // 2M x 2N; wave tile 64 x 64
  const int lrow = l & 15;
  const int totTiles = (N + 255) >> 8;            // 391
  const int split = (blockIdx.x + 8 * blockIdx.y) & (NSPLIT - 1);
  const int mb = blockIdx.y;                      // 16 m-blocks of 128 rows
  const int m0 = mb * 128;
  const int T0 = (totTiles * split) >> 6;
  const int T1 = (totTiles * (split + 1)) >> 6;
  const int nStart = T0 << 8;
  const int nEnd = min(T1 << 8, N);
  const int nSteps = (nEnd - nStart + 127) >> 7;  // 128-wide n-steps
  const int S = nSteps * 4;                       // 4 k128-steps each

  uint32_t K1[16], K2[16];
  #pragma unroll
  for (int s = 0; s < 16; ++s) { K1[s] = 0u; K2[s] = 0u; }

  // stage full buffer for step Hs: 4 A-loads + 4 B-loads per wave (1KB each)
  auto STAGE = [&](int Hs) {
    char* base = smem + (Hs & 1) * 32768;
    int n0 = nStart + (Hs >> 2) * 128;
    int kc128 = Hs & 3;
    #pragma unroll
    for (int t = 0; t < 2; ++t) {
      int g = 2 * w + t;
      int R = mb * 8 + g;                          // global A rowgrp
      const unsigned char* src = qb + (((size_t)(R >> 4) * 4 + kc128) * 16 + (R & 15)) * 2048;
      char* d = base + g * 2048;
      __builtin_amdgcn_global_load_lds((const AS1 int*)(src + l * 16), (AS3 int*)d, 16, 0, 0);
      __builtin_amdgcn_global_load_lds((const AS1 int*)(src + 1024 + l * 16), (AS3 int*)(d + 1024), 16, 0, 0);
    }
    int Tt = n0 >> 8, hi8 = (n0 >> 7) & 1;
    #pragma unroll
    for (int t = 0; t < 2; ++t) {
      int g = 2 * w + t;
      const unsigned char* src = xb + (((size_t)Tt * 4 + kc128) * 16 + hi8 * 8 + g) * 2048;
      char* d = base + 16384 + g * 2048;
      __builtin_amdgcn_global_load_lds((const AS1 int*)(src + l * 16), (AS3 int*)d, 16, 0, 0);
      __builtin_amdgcn_global_load_lds((const AS1 int*)(src + 1024 + l * 16), (AS3 int*)(d + 1024), 16, 0, 0);
    }
  };

  STAGE(0);   // prologue

  fvec4 acc[4][4];
  const fvec4 zero4 = {0.f, 0.f, 0.f, 0.f};       // bias at fold, NOT here

  #pragma unroll 1
  for (int H = 0; H < S; ++H) {
    if ((H & 3) == 0) {
      #pragma unroll
      for (int i = 0; i < 4; ++i)
        #pragma unroll
        for (int j = 0; j < 4; ++j) acc[i][j] = zero4;
    }
    const char* rb = smem + (H & 1) * 32768;

    // stage(H) complete + step H-1 readers retired -> safe to stage H+1
    asm volatile("s_waitcnt vmcnt(0)\n\ts_barrier" ::: "memory");
    __builtin_amdgcn_sched_barrier(0);

    ivec8 Af[4], Bf[4];
    #pragma unroll
    for (int i = 0; i < 4; ++i) {
      const char* p = rb + (wm * 4 + i) * 2048 + l * 16;
      ivec4 alo = *(const ivec4*)p, ahi = *(const ivec4*)(p + 1024);
      Af[i] = __builtin_shufflevector(alo, ahi, 0, 1, 2, 3, 4, 5, 6, 7);
    }
    #pragma unroll
    for (int j = 0; j < 4; ++j) {
      const char* p = rb + 16384 + (wn * 4 + j) * 2048 + l * 16;
      ivec4 blo = *(const ivec4*)p, bhi = *(const ivec4*)(p + 1024);
      Bf[j] = __builtin_shufflevector(blo, bhi, 0, 1, 2, 3, 4, 5, 6, 7);
    }
    if (H + 1 < S) STAGE(H + 1);

    __builtin_amdgcn_s_setprio(1);
    #pragma unroll
    for (int i = 0; i < 4; ++i)
      #pragma unroll
      for (int j = 0; j < 4; ++j)
        acc[i][j] = __builtin_amdgcn_mfma_scale_f32_16x16x128_f8f6f4(
            Af[i], Bf[j], acc[i][j], 0, 0, 0, 127, 0, 127);
    __builtin_amdgcn_s_setprio(0);

    // ---- end of n-step: branchless top-2 fold (+8 bias applied HERE) ----
    if ((H & 3) == 3) {
      int n0 = nStart + (H >> 2) * 128;
      uint32_t msk[4], nb[4];
      #pragma unroll
      for (int j = 0; j < 4; ++j) {
        int n = n0 + wn * 64 + j * 16 + lrow;
        bool valid = n < nEnd;
        msk[j] = valid ? 0xFFFFF800u : 0u;
        nb[j]  = valid ? (uint32_t)(2047 - (n - nStart)) : 0u;
      }
      #pragma unroll
      for (int i = 0; i < 4; ++i)
        #pragma unroll
        for (int j = 0; j < 4; ++j)
          #pragma unroll
          for (int r = 0; r < 4; ++r) {
            int ss = i * 4 + r;
            uint32_t key = (__builtin_bit_cast(uint32_t, acc[i][j][r] + 8.0f) & msk[j]) | nb[j];
            uint32_t lo = min(K1[ss], key);
            K1[ss] = max(K1[ss], key);
            K2[ss] = max(K2[ss], lo);
          }
    }
  }

  // cross-lane top-2 merge over the 16 lanes sharing each query row
  #pragma unroll
  for (int s = 0; s < 16; ++s) {
    uint32_t k1 = K1[s], k2 = K2[s];
    #pragma unroll
    for (int off = 1; off < 16; off <<= 1) {
      uint32_t o1 = (uint32_t)__shfl_xor((int)k1, off, 64);
      uint32_t o2 = (uint32_t)__shfl_xor((int)k2, off, 64);
      uint32_t nk2 = max(min(k1, o1), max(k2, o2));
      k1 = max(k1, o1);
      k2 = nk2;
    }
    if (lrow == 0) {
      int m = m0 + wm * 64 + (s >> 2) * 16 + (l >> 4) * 4 + (s & 3);
      keys[((size_t)m * NSPLIT + split) * 2 + wn] = make_int2((int)k1, (int)k2);
    }
  }
}

// ---------- fallback (no-ws path): R13 structure, f32 -> bf16 on-the-fly ----------
__global__ __launch_bounds__(256)
__attribute__((amdgpu_waves_per_eu(2, 2)))
void nn_mfma_fb(
    const float* __restrict__ qf, const float* __restrict__ xf,
    const float* __restrict__ rnorm,
    int2* __restrict__ keys, int N) {
  __shared__ __align__(1024) char smem[49152];
  const int tid = threadIdx.x;
  const int l = tid & 63, wv = tid >> 6;
  const int lrow = l & 15;
  const int totTiles = (N + 255) >> 8;
  const int split = blockIdx.x;
  const int m0 = blockIdx.y * BM;
  const int nStart = ((totTiles * split) >> 6) << 8;
  const int nEnd = min(((totTiles * (split + 1)) >> 6) << 8, N);

  uint32_t K1[16], K2[16];
  #pragma unroll
  for (int s = 0; s < 16; ++s) { K1[s] = 0u; K2[s] = 0u; }
  const fvec4 zero4 = {0.f, 0.f, 0.f, 0.f};

  auto STAGE = [&](int c, int sn0, int sk0) {
    char* base = smem + c * 24576;
    #pragma unroll
    for (int u = 0; u < 6; ++u) {
      int unit = tid + 256 * u;
      if (unit < 1024) {
        int row = unit >> 2, kg = unit & 3;
        int boff_l = (row >> 4) * 1024 + kg * 256 + (row & 15) * 16;
        const float* s0 = qf + (size_t)(m0 + row) * DIM + sk0 + kg * 8;
        float4 a0 = *(const float4*)s0, a1 = *(const float4*)(s0 + 4);
        float vv[8] = {a0.x,a0.y,a0.z,a0.w,a1.x,a1.y,a1.z,a1.w};
        ivec4 hw;
        #pragma unroll
        for (int t = 0; t < 4; ++t) {
          ushort_t h0 = bf16_rne(vv[2*t]), h1 = bf16_rne(vv[2*t+1]);
          hw[t] = (int)((uint32_t)h0 | ((uint32_t)h1 << 16));
        }
        *(ivec4*)(base + boff_l) = hw;
      } else {
        int u2 = unit - 1024;
        int row = u2 >> 2, kg = u2 & 3;
        int boff_l = 16384 + (row >> 4) * 1024 + kg * 256 + (row & 15) * 16;
        int gr = min(sn0 + row, N - 1);
        float rn = rnorm[gr];
        const float* s0 = xf + (size_t)gr * DIM + sk0 + kg * 8;
        float4 a0 = *(const float4*)s0, a1 = *(const float4*)(s0 + 4);
        float vv[8] = {a0.x*rn,a0.y*rn,a0.z*rn,a0.w*rn,a1.x*rn,a1.y*rn,a1.z*rn,a1.w*rn};
        ivec4 hw;
        #pragma unroll
        for (int t = 0; t < 4; ++t) {
          ushort_t h0 = bf16_rne(vv[2*t]), h1 = bf16_rne(vv[2*t+1]);
          hw[t] = (int)((uint32_t)h0 | ((uint32_t)h1 << 16));
        }
        *(ivec4*)(base + boff_l) = hw;
      }
    }
  };

  const int nTiles = (nEnd - nStart + 127) >> 7;
  const int S = nTiles * 16;
  STAGE(0, nStart, 0);
  if (S > 1) STAGE(1 % 3, nStart, 32);
  __syncthreads();

  fvec4 acc[4][8];
  #pragma unroll 1
  for (int s = 0; s < S; ++s) {
    if ((s & 15) == 0) {
      #pragma unroll
      for (int i = 0; i < 4; ++i)
        #pragma unroll
        for (int j = 0; j < 8; ++j) acc[i][j] = zero4;
    }
    if (s + 2 < S) STAGE((s + 2) % 3, nStart + (((s + 2) >> 4) * 128), ((s + 2) & 15) * 32);
    const char* rb = smem + (s % 3) * 24576;
    bvec8 Ah[4], Bh[8];
    #pragma unroll
    for (int i = 0; i < 4; ++i)
      Ah[i] = __builtin_bit_cast(bvec8, *(const ivec4*)(rb + (wv*4 + i) * 1024 + l * 16));
    #pragma unroll
    for (int j = 0; j < 8; ++j)
      Bh[j] = __builtin_bit_cast(bvec8, *(const ivec4*)(rb + 16384 + j * 1024 + l * 16));
    #pragma unroll
    for (int i = 0; i < 4; ++i)
      #pragma unroll
      for (int j = 0; j < 8; ++j)
        acc[i][j] = __builtin_amdgcn_mfma_f32_16x16x32_bf16(Ah[i], Bh[j], acc[i][j], 0, 0, 0);
    if ((s & 15) == 15) {
      int n0 = nStart + ((s >> 4) * 128);
      uint32_t msk[8], nb[8];
      #pragma unroll
      for (int j = 0; j < 8; ++j) {
        int n = n0 + j * 16 + lrow;
        bool valid = n < nEnd;
        msk[j] = valid ? 0xFFFFF800u : 0u;
        nb[j]  = valid ? (uint32_t)(2047 - (n - nStart)) : 0u;
      }
      #pragma unroll
      for (int i = 0; i < 4; ++i)
        #pragma unroll
        for (int j = 0; j < 8; ++j)
          #pragma unroll
          for (int r = 0; r < 4; ++r) {
            int ss = i * 4 + r;
            uint32_t key = (__builtin_bit_cast(uint32_t, acc[i][j][r] + 8.0f) & msk[j]) | nb[j];
            uint32_t lo = min(K1[ss], key);
            K1[ss] = max(K1[ss], key);
            K2[ss] = max(K2[ss], lo);
          }
    }
    __syncthreads();
  }

  #pragma unroll
  for (int s = 0; s < 16; ++s) {
    uint32_t k1 = K1[s], k2 = K2[s];
    #pragma unroll
    for (int off = 1; off < 16; off <<= 1) {
      uint32_t o1 = (uint32_t)__shfl_xor((int)k1, off, 64);
      uint32_t o2 = (uint32_t)__shfl_xor((int)k2, off, 64);
      uint32_t nk2 = max(min(k1, o1), max(k2, o2));
      k1 = max(k1, o1);
      k2 = nk2;
    }
    if (lrow == 0) {
      int m = m0 + wv * 64 + (s >> 2) * 16 + (l >> 4) * 4 + (s & 3);
      keys[((size_t)m * NSPLIT + split) * 2 + 0] = make_int2((int)k1, (int)k2);
      keys[((size_t)m * NSPLIT + split) * 2 + 1] = make_int2(0, 0);
    }
  }
}

// ---------- finalize: unpack 256 candidate slots, exact f32 rescore, one-hot ----------
__global__ __launch_bounds__(256) void finalize_kernel(
    const int2* __restrict__ keys,
    const float* __restrict__ qf, const float* __restrict__ xf,
    const float* __restrict__ rnorm, const int* __restrict__ y,
    int* __restrict__ out, int N) {
  int m = blockIdx.x;
  int tid = threadIdx.x, l = tid & 63, w = tid >> 6;
  const int totTiles = (N + 255) >> 8;
  __shared__ float sv[256]; __shared__ int si[256];
  __shared__ float swm[4];
  __shared__ float swv[4]; __shared__ int swi[4];
  __shared__ int s_label;
  {
    int slot = tid >> 1;                       // split*2 + wn
    int2 kk = keys[(size_t)m * 128 + slot];
    uint32_t k = (tid & 1) ? (uint32_t)kk.y : (uint32_t)kk.x;
    float v; int idx;
    if (k == 0) { v = -FLT_MAX; idx = 0x7fffffff; }
    else {
      int sp = slot >> 1;
      int nStart = ((totTiles * sp) >> 6) << 8;
      v = __builtin_bit_cast(float, k & 0xFFFFF800u) - 8.0f;
      idx = nStart + 2047 - (int)(k & 0x7FFu);
    }
    sv[tid] = v; si[tid] = idx;
  }
  __syncthreads();
  float v = sv[tid];
  #pragma unroll
  for (int off = 1; off < 64; off <<= 1) v = fmaxf(v, __shfl_xor(v, off, 64));
  if (l == 0) swm[w] = v;
  __syncthreads();
  float svmax = fmaxf(fmaxf(swm[0], swm[1]), fmaxf(swm[2], swm[3]));
  float thresh = svmax - MARGIN;
  float bestv = -FLT_MAX; int besti = 0x7fffffff;
  for (int cc = 0; cc < 64; ++cc) {
    int c = w * 64 + cc;
    float av = sv[c]; int idx = si[c];
    if (av < thresh) continue;  // wave-uniform branch
    const float4* qp = (const float4*)(qf + (size_t)m * DIM);
    const float4* xp = (const float4*)(xf + (size_t)idx * DIM);
    float s = 0.f;
    #pragma unroll
    for (int t = 0; t < 2; ++t) {
      float4 qa = qp[l * 2 + t], xa = xp[l * 2 + t];
      s += qa.x*xa.x + qa.y*xa.y + qa.z*xa.z + qa.w*xa.w;
    }
    #pragma unroll
    for (int off = 1; off < 64; off <<= 1) s += __shfl_xor(s, off, 64);
    float ev = s * rnorm[idx];
    if (ev > bestv || (ev == bestv && idx < besti)) { bestv = ev; besti = idx; }
  }
  if (l == 0) { swv[w] = bestv; swi[w] = besti; }
  __syncthreads();
  if (tid == 0) {
    float bv = swv[0]; int bi = swi[0];
    #pragma unroll
    for (int k = 1; k < 4; ++k)
      if (swv[k] > bv || (swv[k] == bv && swi[k] < bi)) { bv = swv[k]; bi = swi[k]; }
    s_label = y[bi];
  }
  __syncthreads();
  int label = s_label;
  for (int c = tid; c < NUM_CLASSES; c += 256)
    out[(size_t)m * NUM_CLASSES + c] = (c == label) ? 1 : 0;
}

extern "C" void kernel_launch(void* const* d_in, const int* in_sizes, int n_in,
                              void* d_out, int out_size, void* d_ws, size_t ws_size,
                              hipStream_t stream) {
  const float* x = (const float*)d_in[0];   // [N, 512]
  const int*   y = (const int*)d_in[1];     // [N]
  const float* q = (const float*)d_in[2];   // [M, 512]
  int N = in_sizes[0] / DIM;                // 100000
  int M = in_sizes[2] / DIM;                // 2048
  int* out = (int*)d_out;
  int totTiles = (N + 255) >> 8;            // 391
  int padN = totTiles << 8;                 // 100096

  // workspace layout (fp8 blob arrays: ~52MB total)
  size_t off = 0;
  float* rnorm = (float*)((char*)d_ws + off); off += (((size_t)N * 4 + 1023) / 1024) * 1024;
  int2* keys   = (int2*)((char*)d_ws + off);  off += (size_t)M * NSPLIT * 2 * 8;
  unsigned char* qb8 = (unsigned char*)d_ws + off; off += (size_t)M * DIM;
  unsigned char* xb8 = (unsigned char*)d_ws + off; off += (size_t)padN * DIM;
  bool pre = (ws_size >= off);

  if (pre) {
    prep_fp8<<<(padN * 16 + 255) / 256, 256, 0, stream>>>(x, rnorm, xb8, N, padN, 1);
    prep_fp8<<<(M * 16 + 255) / 256, 256, 0, stream>>>(q, nullptr, qb8, M, M, 0);
    dim3 grid(NSPLIT, M / 128);               // 64 x 16 = 1024 blocks, 2/CU resident
    nn_mx<<<grid, 256, 0, stream>>>(qb8, xb8, keys, N);
  } else {
    prep_fp8<<<(N * 16 + 255) / 256, 256, 0, stream>>>(x, rnorm, nullptr, N, N, 1);
    dim3 gridf(NSPLIT, M / BM);               // fallback: bf16 on-the-fly
    nn_mfma_fb<<<gridf, 256, 0, stream>>>(q, x, rnorm, keys, N);
  }
  finalize_kernel<<<M, 256, 0, stream>>>(keys, q, x, rnorm, y, out, N);
}